// Round 2
// baseline (489.252 us; speedup 1.0000x reference)
//
#include <hip/hip_runtime.h>

typedef unsigned short u16;
typedef short bf8v __attribute__((ext_vector_type(8)));
typedef float f4v __attribute__((ext_vector_type(4)));

#define DEV static __device__ __forceinline__

constexpr int BB   = 64;
constexpr int NV   = 21;
constexpr int BN   = BB * NV;       // 1344
constexpr int PNUM = 255;
constexpr int D    = 128;
constexpr int PRED = 96;
constexpr int ROWS = BN * PNUM;     // 342720 = 64 * 5355
constexpr int KH   = D * PNUM;      // 32640 head K (divisible by 32)
constexpr int CH   = 20;            // head K chunks
constexpr int GPC  = KH / 8 / CH;   // 204 k-groups (of 8) per chunk
constexpr float EMA_SCALE = 0.70710678118654752440f;  // 1/sqrt(2)

DEV float bf2f(u16 h) { return __uint_as_float(((unsigned)h) << 16); }
DEV u16 f2bf(float f) {
  unsigned u = __float_as_uint(f);
  return (u16)((u + 0x7fffu + ((u >> 16) & 1u)) >> 16);
}
DEV f4v mfma16(bf8v a, bf8v b, f4v c) {
  return __builtin_amdgcn_mfma_f32_16x16x32_bf16(a, b, c, 0, 0, 0);
}

// LN stats over 128 cols held by the 16 lanes of each quad (8 cols/lane).
DEV void ln128(const f4v acc[8], float mean[4], float rstd[4]) {
#pragma unroll
  for (int r = 0; r < 4; r++) {
    float s = 0.f, s2 = 0.f;
#pragma unroll
    for (int n = 0; n < 8; n++) { float v = acc[n][r]; s += v; s2 += v * v; }
#pragma unroll
    for (int m = 1; m <= 8; m <<= 1) { s += __shfl_xor(s, m, 64); s2 += __shfl_xor(s2, m, 64); }
    mean[r] = s * (1.f / 128.f);
    float var = s2 * (1.f / 128.f) - mean[r] * mean[r];
    rstd[r] = rsqrtf(var + 1e-5f);
  }
}

// ---------------- weight swizzle prepass (fp32 -> bf16 B-fragments) ----------------
// dst[((k>>3)*N + n)*8 + (k&7)] = src[k*N + n]; k >= K zero-filled.
__global__ void swz(const float* __restrict__ src, u16* __restrict__ dst, int K, int N, int Kp) {
  int i = blockIdx.x * 256 + threadIdx.x;
  if (i >= Kp * N) return;
  int k = i / N, n = i - k * N;
  u16 v = (k < K) ? f2bf(src[(size_t)k * N + n]) : (u16)0;
  dst[((size_t)(k >> 3) * N + n) * 8 + (k & 7)] = v;
}

// head_w [d*255+l][96] fp32 -> bf16 fragments in k-order kp = l*128 + d
__global__ void swz_head(const float* __restrict__ src, u16* __restrict__ dst) {
  int i = blockIdx.x * 256 + threadIdx.x;
  if (i >= KH * PRED) return;
  int kp = i / PRED, n = i - kp * PRED;
  int l = kp >> 7, d = kp & 127;
  u16 v = f2bf(src[(size_t)(d * PNUM + l) * PRED + n]);
  dst[((size_t)(kp >> 3) * PRED + n) * 8 + (kp & 7)] = v;
}

// ---------------- K1: fused gather + fp LEMblock + 2 encoder LEMblocks ----------------
// Per block: 64 rows. Per wave: 16 rows; each wave uses only its own 16 LDS rows
// (stride 264: cols 0..255 = h, cols 0..127 reused for z) -> no barriers until epilogue.
__global__ __launch_bounds__(256) void k_lem(
    const float* __restrict__ x,
    const u16* __restrict__ ws1, const float* __restrict__ b1,
    const u16* __restrict__ ws2, const u16* __restrict__ wsr,
    const float* __restrict__ b2, const float* __restrict__ br,
    const float* __restrict__ g, const float* __restrict__ be,
    const u16* __restrict__ wse, const float* __restrict__ eb1,
    const float* __restrict__ eb2, const float* __restrict__ ebr,
    const float* __restrict__ eg, const float* __restrict__ ebe,
    u16* __restrict__ zout) {
  __shared__ __align__(16) u16 hl[64 * 264];
  const int t = threadIdx.x;
  const int lane = t & 63, wid = t >> 6;
  const int quad = lane >> 4, lc = lane & 15;
  const int m0 = wid * 16;
  const int tile = blockIdx.x;
  const int col_base = lc;  // col(n) = n*16 + lc

  // z0 A-fragment straight from global (K=16 real, quads 2,3 zero)
  bf8v az;
  {
    unsigned R = (unsigned)tile * 64u + (unsigned)(m0 + lc);
    unsigned bn = R / 255u;
    unsigned p = R - bn * 255u;
    if (quad < 2) {
      const float* px = x + (size_t)bn * 2048u + p * 8u + quad * 8;
      float4 v0 = *(const float4*)px;
      float4 v1 = *(const float4*)(px + 4);
      az[0] = (short)f2bf(v0.x); az[1] = (short)f2bf(v0.y);
      az[2] = (short)f2bf(v0.z); az[3] = (short)f2bf(v0.w);
      az[4] = (short)f2bf(v1.x); az[5] = (short)f2bf(v1.y);
      az[6] = (short)f2bf(v1.z); az[7] = (short)f2bf(v1.w);
    } else {
#pragma unroll
      for (int j = 0; j < 8; j++) az[j] = (short)0;
    }
  }

  // GEMM1: h = relu(z0 @ W1 + b1), N=256
  {
    f4v a1[16];
#pragma unroll
    for (int n = 0; n < 16; n++) a1[n] = (f4v){0.f, 0.f, 0.f, 0.f};
#pragma unroll
    for (int n = 0; n < 16; n++) {
      bf8v b = *(const bf8v*)(ws1 + ((size_t)(quad * 256 + n * 16 + col_base)) * 8);
      a1[n] = mfma16(az, b, a1[n]);
    }
#pragma unroll
    for (int n = 0; n < 16; n++) {
      int col = n * 16 + col_base;
      float bias = b1[col];
#pragma unroll
      for (int r = 0; r < 4; r++) {
        float v = a1[n][r] + bias;
        hl[(m0 + quad * 4 + r) * 264 + col] = f2bf(v > 0.f ? v : 0.f);
      }
    }
  }

  // GEMM2: y = h @ W2 + z0 @ Wr + biases -> LN -> z (cols 0..127)
  f4v acc[8];
#pragma unroll
  for (int n = 0; n < 8; n++) acc[n] = (f4v){0.f, 0.f, 0.f, 0.f};
#pragma unroll
  for (int ks = 0; ks < 8; ks++) {
    bf8v a = *(const bf8v*)(hl + (m0 + lc) * 264 + ks * 32 + quad * 8);
#pragma unroll
    for (int n = 0; n < 8; n++) {
      bf8v b = *(const bf8v*)(ws2 + ((size_t)((ks * 4 + quad) * 128 + n * 16 + col_base)) * 8);
      acc[n] = mfma16(a, b, acc[n]);
    }
  }
#pragma unroll
  for (int n = 0; n < 8; n++) {
    bf8v b = *(const bf8v*)(wsr + ((size_t)(quad * 128 + n * 16 + col_base)) * 8);
    acc[n] = mfma16(az, b, acc[n]);
  }
#pragma unroll
  for (int n = 0; n < 8; n++) {
    int col = n * 16 + col_base;
    float bias = b2[col] + br[col];
#pragma unroll
    for (int r = 0; r < 4; r++) acc[n][r] += bias;
  }
  {
    float mean[4], rstd[4];
    ln128(acc, mean, rstd);
#pragma unroll
    for (int n = 0; n < 8; n++) {
      int col = n * 16 + col_base;
      float gg = g[col], bb = be[col];
#pragma unroll
      for (int r = 0; r < 4; r++)
        hl[(m0 + quad * 4 + r) * 264 + col] = f2bf((acc[n][r] - mean[r]) * rstd[r] * gg + bb);
    }
  }

  // encoder layers: z -> relu(z@W1+b1) [cols 128..255] -> @W2 + z@Wr -> LN -> z
  float zfin[8][4];  // final layer's normalized output
  for (int L = 0; L < 2; L++) {
    const u16* w1 = wse + (size_t)(L * 3 + 0) * 16384;
    const u16* w2 = wse + (size_t)(L * 3 + 1) * 16384;
    const u16* wr = wse + (size_t)(L * 3 + 2) * 16384;
    f4v ha[8];
#pragma unroll
    for (int n = 0; n < 8; n++) ha[n] = (f4v){0.f, 0.f, 0.f, 0.f};
#pragma unroll
    for (int ks = 0; ks < 4; ks++) {
      bf8v a = *(const bf8v*)(hl + (m0 + lc) * 264 + ks * 32 + quad * 8);
#pragma unroll
      for (int n = 0; n < 8; n++) {
        bf8v b = *(const bf8v*)(w1 + ((size_t)((ks * 4 + quad) * 128 + n * 16 + col_base)) * 8);
        ha[n] = mfma16(a, b, ha[n]);
      }
    }
#pragma unroll
    for (int n = 0; n < 8; n++) {
      int col = n * 16 + col_base;
      float bias = eb1[L * 128 + col];
#pragma unroll
      for (int r = 0; r < 4; r++) {
        float v = ha[n][r] + bias;
        hl[(m0 + quad * 4 + r) * 264 + 128 + col] = f2bf(v > 0.f ? v : 0.f);
      }
    }
#pragma unroll
    for (int n = 0; n < 8; n++) acc[n] = (f4v){0.f, 0.f, 0.f, 0.f};
#pragma unroll
    for (int ks = 0; ks < 4; ks++) {
      bf8v a = *(const bf8v*)(hl + (m0 + lc) * 264 + 128 + ks * 32 + quad * 8);
#pragma unroll
      for (int n = 0; n < 8; n++) {
        bf8v b = *(const bf8v*)(w2 + ((size_t)((ks * 4 + quad) * 128 + n * 16 + col_base)) * 8);
        acc[n] = mfma16(a, b, acc[n]);
      }
    }
#pragma unroll
    for (int ks = 0; ks < 4; ks++) {
      bf8v a = *(const bf8v*)(hl + (m0 + lc) * 264 + ks * 32 + quad * 8);
#pragma unroll
      for (int n = 0; n < 8; n++) {
        bf8v b = *(const bf8v*)(wr + ((size_t)((ks * 4 + quad) * 128 + n * 16 + col_base)) * 8);
        acc[n] = mfma16(a, b, acc[n]);
      }
    }
#pragma unroll
    for (int n = 0; n < 8; n++) {
      int col = n * 16 + col_base;
      float bias = eb2[L * 128 + col] + ebr[L * 128 + col];
#pragma unroll
      for (int r = 0; r < 4; r++) acc[n][r] += bias;
    }
    float mean[4], rstd[4];
    ln128(acc, mean, rstd);
#pragma unroll
    for (int n = 0; n < 8; n++) {
      int col = n * 16 + col_base;
      float gg = eg[L * 128 + col], bb = ebe[L * 128 + col];
#pragma unroll
      for (int r = 0; r < 4; r++) {
        float v = (acc[n][r] - mean[r]) * rstd[r] * gg + bb;
        if (L == 0) hl[(m0 + quad * 4 + r) * 264 + col] = f2bf(v);
        else zfin[n][r] = v;
      }
    }
  }

  // epilogue: stage z3 at stride 136 (overlaps other waves' 264-regions -> barrier first)
  __syncthreads();
#pragma unroll
  for (int n = 0; n < 8; n++) {
    int col = n * 16 + col_base;
#pragma unroll
    for (int r = 0; r < 4; r++)
      hl[(m0 + quad * 4 + r) * 136 + col] = f2bf(zfin[n][r]);
  }
  __syncthreads();
#pragma unroll
  for (int it = 0; it < 4; it++) {
    int idx = t + it * 256;
    int row = idx >> 4, seg = idx & 15;
    *(uint4*)(zout + ((size_t)tile * 64 + row) * 128 + seg * 8) =
        *(const uint4*)(hl + row * 136 + seg * 8);
  }
}

// ---------------- K2: MultiHeadEMA (2-state scan) + residual + silu, IN-PLACE ----------------
// z layout [bn][l][d] bf16; output written back to the same slab (same layout).
__global__ __launch_bounds__(128) void k_ema(
    u16* __restrict__ z,
    const float* __restrict__ pdel, const float* __restrict__ palp,
    const float* __restrict__ pbet, const float* __restrict__ pgam,
    const float* __restrict__ pome) {
  __shared__ __align__(16) u16 zc[64 * 128];
  const int t = threadIdx.x;  // channel d
  const int bn = blockIdx.x;
  float p0 = 1.f / (1.f + __expf(-pdel[t * 2 + 0]));
  float p1 = 1.f / (1.f + __expf(-pdel[t * 2 + 1]));
  float q0 = 1.f - p0 / (1.f + __expf(-palp[t * 2 + 0]));
  float q1 = 1.f - p1 / (1.f + __expf(-palp[t * 2 + 1]));
  float w0 = p0 * pbet[t * 2 + 0] * pgam[t * 2 + 0] * EMA_SCALE;
  float w1 = p1 * pbet[t * 2 + 1] * pgam[t * 2 + 1] * EMA_SCALE;
  float om = pome[t];
  float s0 = 0.f, s1 = 0.f;
  u16* slab = z + (size_t)bn * KH;

  for (int ch = 0; ch < 4; ch++) {
    int nrow = (ch < 3) ? 64 : 63;
    int nval = nrow * 128;
    for (int i = t * 8; i < nval; i += 128 * 8)
      *(uint4*)(zc + i) = *(const uint4*)(slab + ch * 8192 + i);
    __syncthreads();
    for (int j = 0; j < nrow; j++) {
      float xv = bf2f(zc[j * 128 + t]);
      s0 = q0 * s0 + xv;
      s1 = q1 * s1 + xv;
      float v = w0 * s0 + w1 * s1 + om * xv;
      v = v / (1.f + __expf(-v));  // silu
      zc[j * 128 + t] = f2bf(v);
    }
    __syncthreads();
    for (int i = t * 8; i < nval; i += 128 * 8)
      *(uint4*)(slab + ch * 8192 + i) = *(const uint4*)(zc + i);
    __syncthreads();
  }
}

// ---------------- K3: head GEMM partials (K split into 20 chunks of 6528) ----------------
__global__ __launch_bounds__(256) void k_head(
    const u16* __restrict__ u, const u16* __restrict__ whs, float* __restrict__ part) {
  const int t = threadIdx.x;
  const int lane = t & 63, wid = t >> 6;
  const int quad = lane >> 4, lc = lane & 15;
  const int tile = blockIdx.x;  // 0..20
  const int ch = blockIdx.y;    // 0..19
  const int m0 = tile * 64 + wid * 16;
  const u16* Ab = u + (size_t)(m0 + lc) * KH + (size_t)ch * (GPC * 8);
  f4v acc[6];
#pragma unroll
  for (int n = 0; n < 6; n++) acc[n] = (f4v){0.f, 0.f, 0.f, 0.f};
  for (int ks = 0; ks < GPC / 4; ks++) {  // 51 iterations of K=32
    bf8v a = *(const bf8v*)(Ab + ks * 32 + quad * 8);
#pragma unroll
    for (int n = 0; n < 6; n++) {
      bf8v b = *(const bf8v*)(whs + ((size_t)(ch * GPC + ks * 4 + quad) * PRED + n * 16 + lc) * 8);
      acc[n] = mfma16(a, b, acc[n]);
    }
  }
#pragma unroll
  for (int n = 0; n < 6; n++) {
    int col = n * 16 + lc;
#pragma unroll
    for (int r = 0; r < 4; r++)
      part[((size_t)ch * BN + m0 + quad * 4 + r) * PRED + col] = acc[n][r];
  }
}

// ---------------- K4: reduce partials + bias -> fp32 out ----------------
__global__ __launch_bounds__(256) void k_red(
    const float* __restrict__ part, const float* __restrict__ hb, float* __restrict__ out) {
  int i = blockIdx.x * 256 + threadIdx.x;
  if (i >= BN * PRED) return;
  int row = i / PRED, col = i - row * PRED;
  float s = hb[col];
#pragma unroll 5
  for (int c = 0; c < CH; c++) s += part[((size_t)c * BN + row) * PRED + col];
  out[i] = s;
}

// ---------------- host ----------------
extern "C" void kernel_launch(void* const* d_in, const int* in_sizes, int n_in,
                              void* d_out, int out_size, void* d_ws, size_t ws_size,
                              hipStream_t stream) {
  const float* x      = (const float*)d_in[0];
  const float* fp_w1  = (const float*)d_in[1];
  const float* fp_b1  = (const float*)d_in[2];
  const float* fp_w2  = (const float*)d_in[3];
  const float* fp_b2  = (const float*)d_in[4];
  const float* fp_wr  = (const float*)d_in[5];
  const float* fp_br  = (const float*)d_in[6];
  const float* fp_g   = (const float*)d_in[7];
  const float* fp_be  = (const float*)d_in[8];
  const float* enc_w1 = (const float*)d_in[9];
  const float* enc_b1 = (const float*)d_in[10];
  const float* enc_w2 = (const float*)d_in[11];
  const float* enc_b2 = (const float*)d_in[12];
  const float* enc_wr = (const float*)d_in[13];
  const float* enc_br = (const float*)d_in[14];
  const float* enc_g  = (const float*)d_in[15];
  const float* enc_be = (const float*)d_in[16];
  const float* e_del  = (const float*)d_in[17];
  const float* e_alp  = (const float*)d_in[18];
  const float* e_bet  = (const float*)d_in[19];
  const float* e_gam  = (const float*)d_in[20];
  const float* e_om   = (const float*)d_in[21];
  const float* head_w = (const float*)d_in[22];
  const float* head_b = (const float*)d_in[23];

  // ws layout (bytes):
  //   [0, 87736320)            z3 / u  (bf16, [ROWS][128])
  //   [87736320, 98058240)     part    (fp32, [20][1344][96])
  //   [98058240, ...)          swizzled bf16 weights (~6.6 MB)   total ~105 MB
  char* base = (char*)d_ws;
  u16* z3 = (u16*)base;
  const size_t EZB = (size_t)ROWS * 128 * 2;                 // 87,736,320
  float* part = (float*)(base + EZB);
  const size_t PARTB = (size_t)CH * BN * PRED * 4;           // 10,321,920
  u16* wb = (u16*)(base + EZB + PARTB);
  u16* ws1 = wb;                 // 32*256         = 8192
  u16* ws2 = ws1 + 8192;         // 256*128        = 32768
  u16* wsr = ws2 + 32768;        // 32*128         = 4096
  u16* wse = wsr + 4096;         // 6 * 128*128    = 98304
  u16* wsh = wse + 98304;        // 32640*96       = 3,133,440

  swz<<<32, 256, 0, stream>>>(fp_w1, ws1, 16, 256, 32);
  swz<<<128, 256, 0, stream>>>(fp_w2, ws2, 256, 128, 256);
  swz<<<16, 256, 0, stream>>>(fp_wr, wsr, 16, 128, 32);
  for (int l = 0; l < 2; l++) {
    swz<<<64, 256, 0, stream>>>(enc_w1 + (size_t)l * 16384, wse + (size_t)(l * 3 + 0) * 16384, 128, 128, 128);
    swz<<<64, 256, 0, stream>>>(enc_w2 + (size_t)l * 16384, wse + (size_t)(l * 3 + 1) * 16384, 128, 128, 128);
    swz<<<64, 256, 0, stream>>>(enc_wr + (size_t)l * 16384, wse + (size_t)(l * 3 + 2) * 16384, 128, 128, 128);
  }
  swz_head<<<(KH * PRED + 255) / 256, 256, 0, stream>>>(head_w, wsh);

  k_lem<<<ROWS / 64, 256, 0, stream>>>(x, ws1, fp_b1, ws2, wsr, fp_b2, fp_br, fp_g, fp_be,
                                       wse, enc_b1, enc_b2, enc_br, enc_g, enc_be, z3);
  k_ema<<<BN, 128, 0, stream>>>(z3, e_del, e_alp, e_bet, e_gam, e_om);
  k_head<<<dim3(21, CH), 256, 0, stream>>>(z3, wsh, part);
  k_red<<<(BN * PRED + 255) / 256, 256, 0, stream>>>(part, head_b, (float*)d_out);
}

// Round 3
// 488.299 us; speedup vs baseline: 1.0020x; 1.0020x over previous
//
#include <hip/hip_runtime.h>

typedef unsigned short u16;
typedef short bf8v __attribute__((ext_vector_type(8)));
typedef float f4v __attribute__((ext_vector_type(4)));

#define DEV static __device__ __forceinline__

constexpr int BB   = 64;
constexpr int NV   = 21;
constexpr int BN   = BB * NV;       // 1344
constexpr int PNUM = 255;
constexpr int D    = 128;
constexpr int PRED = 96;
constexpr int ROWS = BN * PNUM;     // 342720 = 64 * 5355
constexpr int KH   = D * PNUM;      // 32640 head K
constexpr int CH   = 20;            // head K chunks
constexpr int GPC  = KH / 8 / CH;   // 204 k-groups (of 8) per chunk
constexpr float EMA_SCALE = 0.70710678118654752440f;  // 1/sqrt(2)

DEV float bf2f(u16 h) { return __uint_as_float(((unsigned)h) << 16); }
DEV u16 f2bf(float f) {  // RNE (used only in weight prepass)
  unsigned u = __float_as_uint(f);
  return (u16)((u + 0x7fffu + ((u >> 16) & 1u)) >> 16);
}
// pack two floats to bf16 pair, round-half-up: 2 adds + 1 v_perm
DEV unsigned pkbf2(float a, float b) {
  unsigned ua = __float_as_uint(a) + 0x8000u;
  unsigned ub = __float_as_uint(b) + 0x8000u;
  return __builtin_amdgcn_perm(ub, ua, 0x07060302u);
}
DEV f4v mfma16(bf8v a, bf8v b, f4v c) {
  return __builtin_amdgcn_mfma_f32_16x16x32_bf16(a, b, c, 0, 0, 0);
}

// ---------------- fused weight swizzle prepass (fp32 -> bf16 fragments) ----------------
// frag[((k>>3)*N + n)*8 + (k&7)] = src[k*N + n]; k >= K zero-filled.
// Same buffer serves as A- or B-operand fragments (identical lane mapping).
__global__ void swz_all(
    const float* __restrict__ fw1, const float* __restrict__ fw2,
    const float* __restrict__ fwr, const float* __restrict__ ew1,
    const float* __restrict__ ew2, const float* __restrict__ ewr,
    u16* __restrict__ wb) {
  int b = blockIdx.x;
  const float* src; u16* dst; int K, N, Kp;
  if (b < 32)       { src = fw1; dst = wb;          K = 16;  N = 256; Kp = 32; }
  else if (b < 160) { b -= 32;  src = fw2; dst = wb + 8192;  K = 256; N = 128; Kp = 256; }
  else if (b < 176) { b -= 160; src = fwr; dst = wb + 40960; K = 16;  N = 128; Kp = 32; }
  else {
    int e = (b - 176) >> 6; b = (b - 176) & 63;
    int l = e / 3, w = e - 3 * l;
    const float* basep = (w == 0) ? ew1 : (w == 1) ? ew2 : ewr;
    src = basep + (size_t)l * 16384;
    dst = wb + 45056 + e * 16384;
    K = 128; N = 128; Kp = 128;
  }
  int i = b * 256 + threadIdx.x;
  if (i >= Kp * N) return;
  int k = i / N, n = i - k * N;
  u16 v = (k < K) ? f2bf(src[(size_t)k * N + n]) : (u16)0;
  dst[((size_t)(k >> 3) * N + n) * 8 + (k & 7)] = v;
}

// head_w [d*255+l][96] fp32 -> bf16 fragments in k-order kp = l*128 + d
__global__ void swz_head(const float* __restrict__ src, u16* __restrict__ dst) {
  int i = blockIdx.x * 256 + threadIdx.x;
  if (i >= KH * PRED) return;
  int kp = i / PRED, n = i - kp * PRED;
  int l = kp >> 7, d = kp & 127;
  dst[((size_t)(kp >> 3) * PRED + n) * 8 + (kp & 7)] = f2bf(src[(size_t)(d * PNUM + l) * PRED + n]);
}

// ---------------- K1: fused gather + fp LEMblock + 2 encoder LEMblocks (TRANSPOSED) ----------------
// All GEMMs computed as y^T = W^T x act^T: mfma(A=weight_frag, B=act_frag).
// D layout: lane&15 = data-row, per-lane 4 CONSECUTIVE out-cols (quad*4+r) per acc
// -> packed b64 LDS writes; next-GEMM B-fragments read back as ds_read_b128.
__global__ __launch_bounds__(256) void k_lem(
    const float* __restrict__ x,
    const u16* __restrict__ ws1, const float* __restrict__ b1,
    const u16* __restrict__ ws2, const u16* __restrict__ wsr,
    const float* __restrict__ b2, const float* __restrict__ br,
    const float* __restrict__ g, const float* __restrict__ be,
    const u16* __restrict__ wse, const float* __restrict__ eb1,
    const float* __restrict__ eb2, const float* __restrict__ ebr,
    const float* __restrict__ eg, const float* __restrict__ ebe,
    u16* __restrict__ zout) {
  __shared__ __align__(16) u16 hl[64 * 264];
  const int t = threadIdx.x;
  const int lane = t & 63, wid = t >> 6;
  const int quad = lane >> 4, lc = lane & 15;
  const int m0 = wid * 16;
  const int tile = blockIdx.x;
  u16* rowp = hl + (m0 + lc) * 264;  // this lane's LDS row (cols 0..263)

  // z0^T B-fragment straight from global (K=16 real, quads 2,3 zero)
  bf8v az;
  {
    unsigned R = (unsigned)tile * 64u + (unsigned)(m0 + lc);
    unsigned bn = R / 255u;
    unsigned p = R - bn * 255u;
    if (quad < 2) {
      const float* px = x + (size_t)bn * 2048u + p * 8u + quad * 8;
      float4 v0 = *(const float4*)px;
      float4 v1 = *(const float4*)(px + 4);
      az[0] = (short)f2bf(v0.x); az[1] = (short)f2bf(v0.y);
      az[2] = (short)f2bf(v0.z); az[3] = (short)f2bf(v0.w);
      az[4] = (short)f2bf(v1.x); az[5] = (short)f2bf(v1.y);
      az[6] = (short)f2bf(v1.z); az[7] = (short)f2bf(v1.w);
    } else {
#pragma unroll
      for (int j = 0; j < 8; j++) az[j] = (short)0;
    }
  }

  // GEMM1: h^T = W1^T x z0^T, 256 H-cols = 16 acc groups
  {
    f4v a1[16];
#pragma unroll
    for (int n = 0; n < 16; n++) a1[n] = (f4v){0.f, 0.f, 0.f, 0.f};
#pragma unroll
    for (int n = 0; n < 16; n++) {
      bf8v w = *(const bf8v*)(ws1 + ((size_t)(quad * 256 + n * 16 + lc)) * 8);
      a1[n] = mfma16(w, az, a1[n]);
    }
#pragma unroll
    for (int n = 0; n < 16; n++) {
      float4 bv = *(const float4*)(b1 + n * 16 + quad * 4);
      float v0 = fmaxf(a1[n][0] + bv.x, 0.f), v1 = fmaxf(a1[n][1] + bv.y, 0.f);
      float v2 = fmaxf(a1[n][2] + bv.z, 0.f), v3 = fmaxf(a1[n][3] + bv.w, 0.f);
      uint2 pv = {pkbf2(v0, v1), pkbf2(v2, v3)};
      *(uint2*)(rowp + n * 16 + quad * 4) = pv;  // h at cols 0..255
    }
  }

  // GEMM2: y1^T = W2^T h^T + Wr^T z0^T + biases -> LN -> z1 (cols 0..127)
  f4v acc[8];
#pragma unroll
  for (int n = 0; n < 8; n++) acc[n] = (f4v){0.f, 0.f, 0.f, 0.f};
#pragma unroll
  for (int ks = 0; ks < 8; ks++) {
    bf8v h = *(const bf8v*)(rowp + ks * 32 + quad * 8);
#pragma unroll
    for (int n = 0; n < 8; n++) {
      bf8v w = *(const bf8v*)(ws2 + ((size_t)((ks * 4 + quad) * 128 + n * 16 + lc)) * 8);
      acc[n] = mfma16(w, h, acc[n]);
    }
  }
#pragma unroll
  for (int n = 0; n < 8; n++) {
    bf8v w = *(const bf8v*)(wsr + ((size_t)(quad * 128 + n * 16 + lc)) * 8);
    acc[n] = mfma16(w, az, acc[n]);
  }
  {
    float s = 0.f, s2 = 0.f;
#pragma unroll
    for (int n = 0; n < 8; n++) {
      float4 bv2 = *(const float4*)(b2 + n * 16 + quad * 4);
      float4 bvr = *(const float4*)(br + n * 16 + quad * 4);
      acc[n][0] += bv2.x + bvr.x; acc[n][1] += bv2.y + bvr.y;
      acc[n][2] += bv2.z + bvr.z; acc[n][3] += bv2.w + bvr.w;
#pragma unroll
      for (int r = 0; r < 4; r++) { float v = acc[n][r]; s += v; s2 += v * v; }
    }
    s += __shfl_xor(s, 16, 64); s2 += __shfl_xor(s2, 16, 64);
    s += __shfl_xor(s, 32, 64); s2 += __shfl_xor(s2, 32, 64);
    float mean = s * (1.f / 128.f);
    float rstd = rsqrtf(s2 * (1.f / 128.f) - mean * mean + 1e-5f);
#pragma unroll
    for (int n = 0; n < 8; n++) {
      float4 gv = *(const float4*)(g + n * 16 + quad * 4);
      float4 bv = *(const float4*)(be + n * 16 + quad * 4);
      float v0 = (acc[n][0] - mean) * rstd * gv.x + bv.x;
      float v1 = (acc[n][1] - mean) * rstd * gv.y + bv.y;
      float v2 = (acc[n][2] - mean) * rstd * gv.z + bv.z;
      float v3 = (acc[n][3] - mean) * rstd * gv.w + bv.w;
      uint2 pv = {pkbf2(v0, v1), pkbf2(v2, v3)};
      *(uint2*)(rowp + n * 16 + quad * 4) = pv;  // z1 at cols 0..127
    }
  }

  // encoder layers: z (cols 0..127) -> h (cols 128..255) -> y -> LN -> z
  unsigned pkfin[8][2];  // final layer's packed normalized output
  for (int L = 0; L < 2; L++) {
    const u16* w1p = wse + (size_t)(L * 3 + 0) * 16384;
    const u16* w2p = wse + (size_t)(L * 3 + 1) * 16384;
    const u16* wrp = wse + (size_t)(L * 3 + 2) * 16384;
    f4v ha[8];
#pragma unroll
    for (int n = 0; n < 8; n++) ha[n] = (f4v){0.f, 0.f, 0.f, 0.f};
#pragma unroll
    for (int ks = 0; ks < 4; ks++) {
      bf8v zf = *(const bf8v*)(rowp + ks * 32 + quad * 8);
#pragma unroll
      for (int n = 0; n < 8; n++) {
        bf8v w = *(const bf8v*)(w1p + ((size_t)((ks * 4 + quad) * 128 + n * 16 + lc)) * 8);
        ha[n] = mfma16(w, zf, ha[n]);
      }
    }
#pragma unroll
    for (int n = 0; n < 8; n++) {
      float4 bv = *(const float4*)(eb1 + L * 128 + n * 16 + quad * 4);
      float v0 = fmaxf(ha[n][0] + bv.x, 0.f), v1 = fmaxf(ha[n][1] + bv.y, 0.f);
      float v2 = fmaxf(ha[n][2] + bv.z, 0.f), v3 = fmaxf(ha[n][3] + bv.w, 0.f);
      uint2 pv = {pkbf2(v0, v1), pkbf2(v2, v3)};
      *(uint2*)(rowp + 128 + n * 16 + quad * 4) = pv;
    }
#pragma unroll
    for (int n = 0; n < 8; n++) acc[n] = (f4v){0.f, 0.f, 0.f, 0.f};
#pragma unroll
    for (int ks = 0; ks < 4; ks++) {
      bf8v hf = *(const bf8v*)(rowp + 128 + ks * 32 + quad * 8);
#pragma unroll
      for (int n = 0; n < 8; n++) {
        bf8v w = *(const bf8v*)(w2p + ((size_t)((ks * 4 + quad) * 128 + n * 16 + lc)) * 8);
        acc[n] = mfma16(w, hf, acc[n]);
      }
    }
#pragma unroll
    for (int ks = 0; ks < 4; ks++) {
      bf8v zf = *(const bf8v*)(rowp + ks * 32 + quad * 8);
#pragma unroll
      for (int n = 0; n < 8; n++) {
        bf8v w = *(const bf8v*)(wrp + ((size_t)((ks * 4 + quad) * 128 + n * 16 + lc)) * 8);
        acc[n] = mfma16(w, zf, acc[n]);
      }
    }
    float s = 0.f, s2 = 0.f;
#pragma unroll
    for (int n = 0; n < 8; n++) {
      float4 bv2 = *(const float4*)(eb2 + L * 128 + n * 16 + quad * 4);
      float4 bvr = *(const float4*)(ebr + L * 128 + n * 16 + quad * 4);
      acc[n][0] += bv2.x + bvr.x; acc[n][1] += bv2.y + bvr.y;
      acc[n][2] += bv2.z + bvr.z; acc[n][3] += bv2.w + bvr.w;
#pragma unroll
      for (int r = 0; r < 4; r++) { float v = acc[n][r]; s += v; s2 += v * v; }
    }
    s += __shfl_xor(s, 16, 64); s2 += __shfl_xor(s2, 16, 64);
    s += __shfl_xor(s, 32, 64); s2 += __shfl_xor(s2, 32, 64);
    float mean = s * (1.f / 128.f);
    float rstd = rsqrtf(s2 * (1.f / 128.f) - mean * mean + 1e-5f);
#pragma unroll
    for (int n = 0; n < 8; n++) {
      float4 gv = *(const float4*)(eg + L * 128 + n * 16 + quad * 4);
      float4 bv = *(const float4*)(ebe + L * 128 + n * 16 + quad * 4);
      float v0 = (acc[n][0] - mean) * rstd * gv.x + bv.x;
      float v1 = (acc[n][1] - mean) * rstd * gv.y + bv.y;
      float v2 = (acc[n][2] - mean) * rstd * gv.z + bv.z;
      float v3 = (acc[n][3] - mean) * rstd * gv.w + bv.w;
      unsigned plo = pkbf2(v0, v1), phi = pkbf2(v2, v3);
      if (L == 0) {
        uint2 pv = {plo, phi};
        *(uint2*)(rowp + n * 16 + quad * 4) = pv;
      } else {
        pkfin[n][0] = plo; pkfin[n][1] = phi;
      }
    }
  }

  // epilogue: stage z3 at stride 136, then coalesced global stores
  __syncthreads();
#pragma unroll
  for (int n = 0; n < 8; n++) {
    uint2 pv = {pkfin[n][0], pkfin[n][1]};
    *(uint2*)(hl + (m0 + lc) * 136 + n * 16 + quad * 4) = pv;
  }
  __syncthreads();
#pragma unroll
  for (int it = 0; it < 4; it++) {
    int idx = t + it * 256;
    int row = idx >> 4, seg = idx & 15;
    *(uint4*)(zout + ((size_t)tile * 64 + row) * 128 + seg * 8) =
        *(const uint4*)(hl + row * 136 + seg * 8);
  }
}

// ---------------- K2: MultiHeadEMA (2-state scan) + residual + silu, IN-PLACE ----------------
__global__ __launch_bounds__(128) void k_ema(
    u16* __restrict__ z,
    const float* __restrict__ pdel, const float* __restrict__ palp,
    const float* __restrict__ pbet, const float* __restrict__ pgam,
    const float* __restrict__ pome) {
  __shared__ __align__(16) u16 zc[64 * 128];
  const int t = threadIdx.x;  // channel d
  const int bn = blockIdx.x;
  float p0 = 1.f / (1.f + __expf(-pdel[t * 2 + 0]));
  float p1 = 1.f / (1.f + __expf(-pdel[t * 2 + 1]));
  float q0 = 1.f - p0 / (1.f + __expf(-palp[t * 2 + 0]));
  float q1 = 1.f - p1 / (1.f + __expf(-palp[t * 2 + 1]));
  float w0 = p0 * pbet[t * 2 + 0] * pgam[t * 2 + 0] * EMA_SCALE;
  float w1 = p1 * pbet[t * 2 + 1] * pgam[t * 2 + 1] * EMA_SCALE;
  float om = pome[t];
  float s0 = 0.f, s1 = 0.f;
  u16* slab = z + (size_t)bn * KH;

  for (int ch = 0; ch < 4; ch++) {
    int nrow = (ch < 3) ? 64 : 63;
    int nval = nrow * 128;
    for (int i = t * 8; i < nval; i += 128 * 8)
      *(uint4*)(zc + i) = *(const uint4*)(slab + ch * 8192 + i);
    __syncthreads();
    for (int j0 = 0; j0 < nrow; j0 += 8) {
      float xs[8];
#pragma unroll
      for (int jj = 0; jj < 8; jj++)
        if (j0 + jj < nrow) xs[jj] = bf2f(zc[(j0 + jj) * 128 + t]);
#pragma unroll
      for (int jj = 0; jj < 8; jj++)
        if (j0 + jj < nrow) {
          float xv = xs[jj];
          s0 = q0 * s0 + xv;
          s1 = q1 * s1 + xv;
          float v = w0 * s0 + w1 * s1 + om * xv;
          xs[jj] = v / (1.f + __expf(-v));  // silu
        }
#pragma unroll
      for (int jj = 0; jj < 8; jj++)
        if (j0 + jj < nrow)
          zc[(j0 + jj) * 128 + t] = (u16)((__float_as_uint(xs[jj]) + 0x8000u) >> 16);
    }
    __syncthreads();
    for (int i = t * 8; i < nval; i += 128 * 8)
      *(uint4*)(slab + ch * 8192 + i) = *(const uint4*)(zc + i);
    __syncthreads();
  }
}

// ---------------- K3: head GEMM partials (K split into 20 chunks of 1632) ----------------
__global__ __launch_bounds__(256) void k_head(
    const u16* __restrict__ u, const u16* __restrict__ whs, float* __restrict__ part) {
  const int t = threadIdx.x;
  const int lane = t & 63, wid = t >> 6;
  const int quad = lane >> 4, lc = lane & 15;
  const int tile = blockIdx.x;  // 0..20
  const int ch = blockIdx.y;    // 0..19
  const int m0 = tile * 64 + wid * 16;
  const u16* Ab = u + (size_t)(m0 + lc) * KH + (size_t)ch * (GPC * 8);
  f4v acc[6];
#pragma unroll
  for (int n = 0; n < 6; n++) acc[n] = (f4v){0.f, 0.f, 0.f, 0.f};
  for (int ks = 0; ks < GPC / 4; ks++) {  // 51 iterations of K=32
    bf8v a = *(const bf8v*)(Ab + ks * 32 + quad * 8);
#pragma unroll
    for (int n = 0; n < 6; n++) {
      bf8v b = *(const bf8v*)(whs + ((size_t)(ch * GPC + ks * 4 + quad) * PRED + n * 16 + lc) * 8);
      acc[n] = mfma16(a, b, acc[n]);
    }
  }
#pragma unroll
  for (int n = 0; n < 6; n++) {
    int col = n * 16 + lc;
#pragma unroll
    for (int r = 0; r < 4; r++)
      part[((size_t)ch * BN + m0 + quad * 4 + r) * PRED + col] = acc[n][r];
  }
}

// ---------------- K4: reduce partials + bias -> fp32 out ----------------
__global__ __launch_bounds__(256) void k_red(
    const float* __restrict__ part, const float* __restrict__ hb, float* __restrict__ out) {
  int i = blockIdx.x * 256 + threadIdx.x;
  if (i >= BN * PRED) return;
  int row = i / PRED, col = i - row * PRED;
  float s = hb[col];
#pragma unroll 5
  for (int c = 0; c < CH; c++) s += part[((size_t)c * BN + row) * PRED + col];
  out[i] = s;
}

// ---------------- host ----------------
extern "C" void kernel_launch(void* const* d_in, const int* in_sizes, int n_in,
                              void* d_out, int out_size, void* d_ws, size_t ws_size,
                              hipStream_t stream) {
  const float* x      = (const float*)d_in[0];
  const float* fp_w1  = (const float*)d_in[1];
  const float* fp_b1  = (const float*)d_in[2];
  const float* fp_w2  = (const float*)d_in[3];
  const float* fp_b2  = (const float*)d_in[4];
  const float* fp_wr  = (const float*)d_in[5];
  const float* fp_br  = (const float*)d_in[6];
  const float* fp_g   = (const float*)d_in[7];
  const float* fp_be  = (const float*)d_in[8];
  const float* enc_w1 = (const float*)d_in[9];
  const float* enc_b1 = (const float*)d_in[10];
  const float* enc_w2 = (const float*)d_in[11];
  const float* enc_b2 = (const float*)d_in[12];
  const float* enc_wr = (const float*)d_in[13];
  const float* enc_br = (const float*)d_in[14];
  const float* enc_g  = (const float*)d_in[15];
  const float* enc_be = (const float*)d_in[16];
  const float* e_del  = (const float*)d_in[17];
  const float* e_alp  = (const float*)d_in[18];
  const float* e_bet  = (const float*)d_in[19];
  const float* e_gam  = (const float*)d_in[20];
  const float* e_om   = (const float*)d_in[21];
  const float* head_w = (const float*)d_in[22];
  const float* head_b = (const float*)d_in[23];

  // ws layout (bytes):
  //   [0, 87736320)            z3 / u  (bf16, [ROWS][128])
  //   [87736320, 98058240)     part    (fp32, [20][1344][96])
  //   [98058240, ...)          swizzled bf16 weights (~6.6 MB)
  char* base = (char*)d_ws;
  u16* z3 = (u16*)base;
  const size_t EZB = (size_t)ROWS * 128 * 2;        // 87,736,320
  float* part = (float*)(base + EZB);
  const size_t PARTB = (size_t)CH * BN * PRED * 4;  // 10,321,920
  u16* wb = (u16*)(base + EZB + PARTB);
  // wb offsets (u16): ws1=0(8192), ws2=8192(32768), wsr=40960(4096),
  //                   wse=45056(6*16384), wsh=143360(32640*96)
  u16* ws1 = wb;
  u16* ws2 = wb + 8192;
  u16* wsr = wb + 40960;
  u16* wse = wb + 45056;
  u16* wsh = wb + 143360;

  swz_all<<<560, 256, 0, stream>>>(fp_w1, fp_w2, fp_wr, enc_w1, enc_w2, enc_wr, wb);
  swz_head<<<(KH * PRED + 255) / 256, 256, 0, stream>>>(head_w, wsh);

  k_lem<<<ROWS / 64, 256, 0, stream>>>(x, ws1, fp_b1, ws2, wsr, fp_b2, fp_br, fp_g, fp_be,
                                       wse, enc_b1, enc_b2, enc_br, enc_g, enc_be, z3);
  k_ema<<<BN, 128, 0, stream>>>(z3, e_del, e_alp, e_bet, e_gam, e_om);
  k_head<<<dim3(21, CH), 256, 0, stream>>>(z3, wsh, part);
  k_red<<<(BN * PRED + 255) / 256, 256, 0, stream>>>(part, head_b, (float*)d_out);
}

// Round 4
// 444.296 us; speedup vs baseline: 1.1012x; 1.0990x over previous
//
#include <hip/hip_runtime.h>

typedef unsigned short u16;
typedef short bf8v __attribute__((ext_vector_type(8)));
typedef float f4v __attribute__((ext_vector_type(4)));

#define DEV static __device__ __forceinline__

constexpr int BB   = 64;
constexpr int NV   = 21;
constexpr int BN   = BB * NV;       // 1344
constexpr int PNUM = 255;
constexpr int D    = 128;
constexpr int PRED = 96;
constexpr int ROWS = BN * PNUM;     // 342720 = 64 * 5355
constexpr int KH   = D * PNUM;      // 32640 head K
constexpr int CH   = 30;            // head K chunks (21x30 = 630 blocks)
constexpr int KPC  = KH / CH;       // 1088 = 34*32
constexpr int HITER = KPC / 32;     // 34
constexpr int LSTR = 266;           // LDS row stride (odd dword count -> conflict-free)
constexpr float EMA_SCALE = 0.70710678118654752440f;  // 1/sqrt(2)

DEV float bf2f(u16 h) { return __uint_as_float(((unsigned)h) << 16); }
DEV u16 f2bf(float f) {  // RNE (weight prepass only)
  unsigned u = __float_as_uint(f);
  return (u16)((u + 0x7fffu + ((u >> 16) & 1u)) >> 16);
}
// pack two floats to bf16 pair (round-half-up): D = bf16(a) | bf16(b)<<16
DEV unsigned pkbf2(float a, float b) {
  unsigned ua = __float_as_uint(a) + 0x8000u;
  unsigned ub = __float_as_uint(b) + 0x8000u;
  return __builtin_amdgcn_perm(ub, ua, 0x07060302u);
}
DEV f4v mfma16(bf8v a, bf8v b, f4v c) {
  return __builtin_amdgcn_mfma_f32_16x16x32_bf16(a, b, c, 0, 0, 0);
}

// ---------------- fused weight swizzle prepass (fp32 -> bf16 fragments) ----------------
// frag[((k>>3)*N + n)*8 + (k&7)] = src[k*N + n]; k >= K zero-filled.
__global__ void swz_all(
    const float* __restrict__ fw1, const float* __restrict__ fw2,
    const float* __restrict__ fwr, const float* __restrict__ ew1,
    const float* __restrict__ ew2, const float* __restrict__ ewr,
    const float* __restrict__ hw, u16* __restrict__ wb, u16* __restrict__ wsh) {
  int b = blockIdx.x;
  if (b >= 560) {  // head_w [d*255+l][96] -> fragments in k-order kp = l*128 + d
    int i = (b - 560) * 256 + threadIdx.x;
    if (i >= KH * PRED) return;
    int kp = i / PRED, n = i - kp * PRED;
    int l = kp >> 7, d = kp & 127;
    wsh[((size_t)(kp >> 3) * PRED + n) * 8 + (kp & 7)] =
        f2bf(hw[(size_t)(d * PNUM + l) * PRED + n]);
    return;
  }
  const float* src; u16* dst; int K, N, Kp;
  if (b < 32)       { src = fw1; dst = wb;          K = 16;  N = 256; Kp = 32; }
  else if (b < 160) { b -= 32;  src = fw2; dst = wb + 8192;  K = 256; N = 128; Kp = 256; }
  else if (b < 176) { b -= 160; src = fwr; dst = wb + 40960; K = 16;  N = 128; Kp = 32; }
  else {
    int e = (b - 176) >> 6; b = (b - 176) & 63;
    int l = e / 3, w = e - 3 * l;
    const float* basep = (w == 0) ? ew1 : (w == 1) ? ew2 : ewr;
    src = basep + (size_t)l * 16384;
    dst = wb + 45056 + e * 16384;
    K = 128; N = 128; Kp = 128;
  }
  int i = b * 256 + threadIdx.x;
  if (i >= Kp * N) return;
  int k = i / N, n = i - k * N;
  u16 v = (k < K) ? f2bf(src[(size_t)k * N + n]) : (u16)0;
  dst[((size_t)(k >> 3) * N + n) * 8 + (k & 7)] = v;
}

// ---------------- K1: fused gather + fp LEMblock + 2 encoder LEMblocks ----------------
// Transposed GEMMs: mfma(A=weight_frag, B=act_frag). 128-thread blocks, 2 waves;
// each wave owns 2 independent 16-row tiles (T=2): every weight fragment load
// feeds 2 MFMAs. Explicit double-buffered prefetch of weights + LDS fragments.
__global__ __launch_bounds__(128, 2) void k_lem(
    const float* __restrict__ x,
    const u16* __restrict__ ws1, const float* __restrict__ b1,
    const u16* __restrict__ ws2, const u16* __restrict__ wsr,
    const float* __restrict__ b2, const float* __restrict__ br,
    const float* __restrict__ g, const float* __restrict__ be,
    const u16* __restrict__ wse, const float* __restrict__ eb1,
    const float* __restrict__ eb2, const float* __restrict__ ebr,
    const float* __restrict__ eg, const float* __restrict__ ebe,
    u16* __restrict__ zout) {
  __shared__ __align__(16) u16 hl[64 * LSTR];
  const int t = threadIdx.x;
  const int lane = t & 63, wid = t >> 6;   // wid 0..1
  const int quad = lane >> 4, lc = lane & 15;
  const int tile = blockIdx.x;
  u16* rowp0 = hl + (wid * 32 + lc) * LSTR;
  u16* rowp1 = hl + (wid * 32 + 16 + lc) * LSTR;

  // z0 fragments straight from global (K=16 real, quads 2,3 zero)
  bf8v az0, az1;
  {
    unsigned R0 = (unsigned)tile * 64u + (unsigned)(wid * 32 + lc);
#pragma unroll
    for (int tt = 0; tt < 2; tt++) {
      unsigned R = R0 + tt * 16;
      unsigned bn = R / 255u;
      unsigned p = R - bn * 255u;
      bf8v az;
      if (quad < 2) {
        const float* px = x + (size_t)bn * 2048u + p * 8u + quad * 8;
        float4 v0 = *(const float4*)px;
        float4 v1 = *(const float4*)(px + 4);
        az[0] = (short)f2bf(v0.x); az[1] = (short)f2bf(v0.y);
        az[2] = (short)f2bf(v0.z); az[3] = (short)f2bf(v0.w);
        az[4] = (short)f2bf(v1.x); az[5] = (short)f2bf(v1.y);
        az[6] = (short)f2bf(v1.z); az[7] = (short)f2bf(v1.w);
      } else {
#pragma unroll
        for (int j = 0; j < 8; j++) az[j] = (short)0;
      }
      if (tt == 0) az0 = az; else az1 = az;
    }
  }

  // GEMM1: h = W1^T z0 (256 cols, two halves of 8 n-groups)
#pragma unroll
  for (int half = 0; half < 2; half++) {
    bf8v w[8];
#pragma unroll
    for (int n = 0; n < 8; n++)
      w[n] = *(const bf8v*)(ws1 + ((size_t)(quad * 256 + (half * 8 + n) * 16 + lc)) * 8);
    f4v h0[8], h1[8];
#pragma unroll
    for (int n = 0; n < 8; n++) {
      h0[n] = mfma16(w[n], az0, (f4v){0.f, 0.f, 0.f, 0.f});
      h1[n] = mfma16(w[n], az1, (f4v){0.f, 0.f, 0.f, 0.f});
    }
#pragma unroll
    for (int n = 0; n < 8; n++) {
      int col = (half * 8 + n) * 16 + quad * 4;
      float4 bv = *(const float4*)(b1 + col);
      float a0 = fmaxf(h0[n][0] + bv.x, 0.f), a1 = fmaxf(h0[n][1] + bv.y, 0.f);
      float a2 = fmaxf(h0[n][2] + bv.z, 0.f), a3 = fmaxf(h0[n][3] + bv.w, 0.f);
      uint2 p0 = {pkbf2(a0, a1), pkbf2(a2, a3)};
      *(uint2*)(rowp0 + col) = p0;
      float c0 = fmaxf(h1[n][0] + bv.x, 0.f), c1 = fmaxf(h1[n][1] + bv.y, 0.f);
      float c2 = fmaxf(h1[n][2] + bv.z, 0.f), c3 = fmaxf(h1[n][3] + bv.w, 0.f);
      uint2 p1 = {pkbf2(c0, c1), pkbf2(c2, c3)};
      *(uint2*)(rowp1 + col) = p1;
    }
  }

  // GEMM2: y1 = W2^T h + Wr^T z0 + biases -> LN -> z1 (cols 0..127)
  f4v ac0[8], ac1[8];
#pragma unroll
  for (int n = 0; n < 8; n++) { ac0[n] = (f4v){0.f,0.f,0.f,0.f}; ac1[n] = (f4v){0.f,0.f,0.f,0.f}; }
  {
    bf8v wq[2][8], hf0[2], hf1[2];
#pragma unroll
    for (int n = 0; n < 8; n++)
      wq[0][n] = *(const bf8v*)(ws2 + ((size_t)(quad * 128 + n * 16 + lc)) * 8);
    hf0[0] = *(const bf8v*)(rowp0 + quad * 8);
    hf1[0] = *(const bf8v*)(rowp1 + quad * 8);
#pragma unroll
    for (int ks = 0; ks < 8; ks++) {
      int cur = ks & 1, nxt = cur ^ 1;
      if (ks < 7) {
#pragma unroll
        for (int n = 0; n < 8; n++)
          wq[nxt][n] = *(const bf8v*)(ws2 + ((size_t)(((ks + 1) * 4 + quad) * 128 + n * 16 + lc)) * 8);
        hf0[nxt] = *(const bf8v*)(rowp0 + (ks + 1) * 32 + quad * 8);
        hf1[nxt] = *(const bf8v*)(rowp1 + (ks + 1) * 32 + quad * 8);
      }
#pragma unroll
      for (int n = 0; n < 8; n++) {
        ac0[n] = mfma16(wq[cur][n], hf0[cur], ac0[n]);
        ac1[n] = mfma16(wq[cur][n], hf1[cur], ac1[n]);
      }
    }
#pragma unroll
    for (int n = 0; n < 8; n++) {
      bf8v w = *(const bf8v*)(wsr + ((size_t)(quad * 128 + n * 16 + lc)) * 8);
      ac0[n] = mfma16(w, az0, ac0[n]);
      ac1[n] = mfma16(w, az1, ac1[n]);
    }
  }
  {  // bias + LN -> z1
    float s0 = 0.f, q0 = 0.f, s1 = 0.f, q1 = 0.f;
#pragma unroll
    for (int n = 0; n < 8; n++) {
      int col = n * 16 + quad * 4;
      float4 bv2 = *(const float4*)(b2 + col);
      float4 bvr = *(const float4*)(br + col);
      ac0[n][0] += bv2.x + bvr.x; ac0[n][1] += bv2.y + bvr.y;
      ac0[n][2] += bv2.z + bvr.z; ac0[n][3] += bv2.w + bvr.w;
      ac1[n][0] += bv2.x + bvr.x; ac1[n][1] += bv2.y + bvr.y;
      ac1[n][2] += bv2.z + bvr.z; ac1[n][3] += bv2.w + bvr.w;
#pragma unroll
      for (int r = 0; r < 4; r++) {
        float v0 = ac0[n][r], v1 = ac1[n][r];
        s0 += v0; q0 += v0 * v0; s1 += v1; q1 += v1 * v1;
      }
    }
    s0 += __shfl_xor(s0, 16, 64); q0 += __shfl_xor(q0, 16, 64);
    s0 += __shfl_xor(s0, 32, 64); q0 += __shfl_xor(q0, 32, 64);
    s1 += __shfl_xor(s1, 16, 64); q1 += __shfl_xor(q1, 16, 64);
    s1 += __shfl_xor(s1, 32, 64); q1 += __shfl_xor(q1, 32, 64);
    float m0 = s0 * (1.f / 128.f), m1 = s1 * (1.f / 128.f);
    float r0 = rsqrtf(q0 * (1.f / 128.f) - m0 * m0 + 1e-5f);
    float r1 = rsqrtf(q1 * (1.f / 128.f) - m1 * m1 + 1e-5f);
#pragma unroll
    for (int n = 0; n < 8; n++) {
      int col = n * 16 + quad * 4;
      float4 gv = *(const float4*)(g + col);
      float4 bv = *(const float4*)(be + col);
      uint2 p0 = {pkbf2((ac0[n][0]-m0)*r0*gv.x+bv.x, (ac0[n][1]-m0)*r0*gv.y+bv.y),
                  pkbf2((ac0[n][2]-m0)*r0*gv.z+bv.z, (ac0[n][3]-m0)*r0*gv.w+bv.w)};
      *(uint2*)(rowp0 + col) = p0;
      uint2 p1 = {pkbf2((ac1[n][0]-m1)*r1*gv.x+bv.x, (ac1[n][1]-m1)*r1*gv.y+bv.y),
                  pkbf2((ac1[n][2]-m1)*r1*gv.z+bv.z, (ac1[n][3]-m1)*r1*gv.w+bv.w)};
      *(uint2*)(rowp1 + col) = p1;
    }
  }

  // encoder layers: z (cols 0..127) -> h (cols 128..255) -> y -> LN -> z
  unsigned fin0[8][2], fin1[8][2];
#pragma unroll 1
  for (int L = 0; L < 2; L++) {
    const u16* w1p = wse + (size_t)(L * 3 + 0) * 16384;
    const u16* w2p = wse + (size_t)(L * 3 + 1) * 16384;
    const u16* wrp = wse + (size_t)(L * 3 + 2) * 16384;
    // GEMM-A: h = relu(W1^T z + b1)
    f4v ha0[8], ha1[8];
#pragma unroll
    for (int n = 0; n < 8; n++) { ha0[n] = (f4v){0.f,0.f,0.f,0.f}; ha1[n] = (f4v){0.f,0.f,0.f,0.f}; }
    {
      bf8v wq[2][8], zf0[2], zf1[2];
#pragma unroll
      for (int n = 0; n < 8; n++)
        wq[0][n] = *(const bf8v*)(w1p + ((size_t)(quad * 128 + n * 16 + lc)) * 8);
      zf0[0] = *(const bf8v*)(rowp0 + quad * 8);
      zf1[0] = *(const bf8v*)(rowp1 + quad * 8);
#pragma unroll
      for (int ks = 0; ks < 4; ks++) {
        int cur = ks & 1, nxt = cur ^ 1;
        if (ks < 3) {
#pragma unroll
          for (int n = 0; n < 8; n++)
            wq[nxt][n] = *(const bf8v*)(w1p + ((size_t)(((ks + 1) * 4 + quad) * 128 + n * 16 + lc)) * 8);
          zf0[nxt] = *(const bf8v*)(rowp0 + (ks + 1) * 32 + quad * 8);
          zf1[nxt] = *(const bf8v*)(rowp1 + (ks + 1) * 32 + quad * 8);
        }
#pragma unroll
        for (int n = 0; n < 8; n++) {
          ha0[n] = mfma16(wq[cur][n], zf0[cur], ha0[n]);
          ha1[n] = mfma16(wq[cur][n], zf1[cur], ha1[n]);
        }
      }
    }
#pragma unroll
    for (int n = 0; n < 8; n++) {
      int col = n * 16 + quad * 4;
      float4 bv = *(const float4*)(eb1 + L * 128 + col);
      uint2 p0 = {pkbf2(fmaxf(ha0[n][0]+bv.x,0.f), fmaxf(ha0[n][1]+bv.y,0.f)),
                  pkbf2(fmaxf(ha0[n][2]+bv.z,0.f), fmaxf(ha0[n][3]+bv.w,0.f))};
      *(uint2*)(rowp0 + 128 + col) = p0;
      uint2 p1 = {pkbf2(fmaxf(ha1[n][0]+bv.x,0.f), fmaxf(ha1[n][1]+bv.y,0.f)),
                  pkbf2(fmaxf(ha1[n][2]+bv.z,0.f), fmaxf(ha1[n][3]+bv.w,0.f))};
      *(uint2*)(rowp1 + 128 + col) = p1;
    }
    // GEMM-B: y = W2^T h + Wr^T z
#pragma unroll
    for (int n = 0; n < 8; n++) { ac0[n] = (f4v){0.f,0.f,0.f,0.f}; ac1[n] = (f4v){0.f,0.f,0.f,0.f}; }
    {
      bf8v wq[2][8], hf0[2], hf1[2];
#pragma unroll
      for (int n = 0; n < 8; n++)
        wq[0][n] = *(const bf8v*)(w2p + ((size_t)(quad * 128 + n * 16 + lc)) * 8);
      hf0[0] = *(const bf8v*)(rowp0 + 128 + quad * 8);
      hf1[0] = *(const bf8v*)(rowp1 + 128 + quad * 8);
#pragma unroll
      for (int ks = 0; ks < 4; ks++) {
        int cur = ks & 1, nxt = cur ^ 1;
        if (ks < 3) {
#pragma unroll
          for (int n = 0; n < 8; n++)
            wq[nxt][n] = *(const bf8v*)(w2p + ((size_t)(((ks + 1) * 4 + quad) * 128 + n * 16 + lc)) * 8);
          hf0[nxt] = *(const bf8v*)(rowp0 + 128 + (ks + 1) * 32 + quad * 8);
          hf1[nxt] = *(const bf8v*)(rowp1 + 128 + (ks + 1) * 32 + quad * 8);
        }
#pragma unroll
        for (int n = 0; n < 8; n++) {
          ac0[n] = mfma16(wq[cur][n], hf0[cur], ac0[n]);
          ac1[n] = mfma16(wq[cur][n], hf1[cur], ac1[n]);
        }
      }
      // + Wr^T z
#pragma unroll
      for (int n = 0; n < 8; n++)
        wq[0][n] = *(const bf8v*)(wrp + ((size_t)(quad * 128 + n * 16 + lc)) * 8);
      hf0[0] = *(const bf8v*)(rowp0 + quad * 8);
      hf1[0] = *(const bf8v*)(rowp1 + quad * 8);
#pragma unroll
      for (int ks = 0; ks < 4; ks++) {
        int cur = ks & 1, nxt = cur ^ 1;
        if (ks < 3) {
#pragma unroll
          for (int n = 0; n < 8; n++)
            wq[nxt][n] = *(const bf8v*)(wrp + ((size_t)(((ks + 1) * 4 + quad) * 128 + n * 16 + lc)) * 8);
          hf0[nxt] = *(const bf8v*)(rowp0 + (ks + 1) * 32 + quad * 8);
          hf1[nxt] = *(const bf8v*)(rowp1 + (ks + 1) * 32 + quad * 8);
        }
#pragma unroll
        for (int n = 0; n < 8; n++) {
          ac0[n] = mfma16(wq[cur][n], hf0[cur], ac0[n]);
          ac1[n] = mfma16(wq[cur][n], hf1[cur], ac1[n]);
        }
      }
    }
    // bias + LN
    float s0 = 0.f, q0 = 0.f, s1 = 0.f, q1 = 0.f;
#pragma unroll
    for (int n = 0; n < 8; n++) {
      int col = n * 16 + quad * 4;
      float4 bv2 = *(const float4*)(eb2 + L * 128 + col);
      float4 bvr = *(const float4*)(ebr + L * 128 + col);
      ac0[n][0] += bv2.x + bvr.x; ac0[n][1] += bv2.y + bvr.y;
      ac0[n][2] += bv2.z + bvr.z; ac0[n][3] += bv2.w + bvr.w;
      ac1[n][0] += bv2.x + bvr.x; ac1[n][1] += bv2.y + bvr.y;
      ac1[n][2] += bv2.z + bvr.z; ac1[n][3] += bv2.w + bvr.w;
#pragma unroll
      for (int r = 0; r < 4; r++) {
        float v0 = ac0[n][r], v1 = ac1[n][r];
        s0 += v0; q0 += v0 * v0; s1 += v1; q1 += v1 * v1;
      }
    }
    s0 += __shfl_xor(s0, 16, 64); q0 += __shfl_xor(q0, 16, 64);
    s0 += __shfl_xor(s0, 32, 64); q0 += __shfl_xor(q0, 32, 64);
    s1 += __shfl_xor(s1, 16, 64); q1 += __shfl_xor(q1, 16, 64);
    s1 += __shfl_xor(s1, 32, 64); q1 += __shfl_xor(q1, 32, 64);
    float m0 = s0 * (1.f / 128.f), m1 = s1 * (1.f / 128.f);
    float r0 = rsqrtf(q0 * (1.f / 128.f) - m0 * m0 + 1e-5f);
    float r1 = rsqrtf(q1 * (1.f / 128.f) - m1 * m1 + 1e-5f);
#pragma unroll
    for (int n = 0; n < 8; n++) {
      int col = n * 16 + quad * 4;
      float4 gv = *(const float4*)(eg + L * 128 + col);
      float4 bv = *(const float4*)(ebe + L * 128 + col);
      unsigned a0 = pkbf2((ac0[n][0]-m0)*r0*gv.x+bv.x, (ac0[n][1]-m0)*r0*gv.y+bv.y);
      unsigned a1 = pkbf2((ac0[n][2]-m0)*r0*gv.z+bv.z, (ac0[n][3]-m0)*r0*gv.w+bv.w);
      unsigned c0 = pkbf2((ac1[n][0]-m1)*r1*gv.x+bv.x, (ac1[n][1]-m1)*r1*gv.y+bv.y);
      unsigned c1 = pkbf2((ac1[n][2]-m1)*r1*gv.z+bv.z, (ac1[n][3]-m1)*r1*gv.w+bv.w);
      if (L == 0) {
        uint2 p0 = {a0, a1}; *(uint2*)(rowp0 + col) = p0;
        uint2 p1 = {c0, c1}; *(uint2*)(rowp1 + col) = p1;
      } else {
        fin0[n][0] = a0; fin0[n][1] = a1;
        fin1[n][0] = c0; fin1[n][1] = c1;
      }
    }
  }

  // epilogue: stage z3 in own rows (cols 0..127, z dead), barrier, coalesced store
#pragma unroll
  for (int n = 0; n < 8; n++) {
    int col = n * 16 + quad * 4;
    uint2 p0 = {fin0[n][0], fin0[n][1]}; *(uint2*)(rowp0 + col) = p0;
    uint2 p1 = {fin1[n][0], fin1[n][1]}; *(uint2*)(rowp1 + col) = p1;
  }
  __syncthreads();
#pragma unroll
  for (int it = 0; it < 8; it++) {
    int idx = t + it * 128;
    int row = idx >> 4, seg = idx & 15;
    *(uint4*)(zout + ((size_t)tile * 64 + row) * 128 + seg * 8) =
        *(const uint4*)(hl + row * LSTR + seg * 8);
  }
}

// ---------------- K2: MultiHeadEMA (2-state scan) + residual + silu, IN-PLACE ----------------
__global__ __launch_bounds__(128) void k_ema(
    u16* __restrict__ z,
    const float* __restrict__ pdel, const float* __restrict__ palp,
    const float* __restrict__ pbet, const float* __restrict__ pgam,
    const float* __restrict__ pome) {
  __shared__ __align__(16) u16 zc[64 * 128];
  const int t = threadIdx.x;  // channel d
  const int bn = blockIdx.x;
  float p0 = 1.f / (1.f + __expf(-pdel[t * 2 + 0]));
  float p1 = 1.f / (1.f + __expf(-pdel[t * 2 + 1]));
  float q0 = 1.f - p0 / (1.f + __expf(-palp[t * 2 + 0]));
  float q1 = 1.f - p1 / (1.f + __expf(-palp[t * 2 + 1]));
  float w0 = p0 * pbet[t * 2 + 0] * pgam[t * 2 + 0] * EMA_SCALE;
  float w1 = p1 * pbet[t * 2 + 1] * pgam[t * 2 + 1] * EMA_SCALE;
  float om = pome[t];
  float s0 = 0.f, s1 = 0.f;
  u16* slab = z + (size_t)bn * KH;

  for (int ch = 0; ch < 4; ch++) {
    int nrow = (ch < 3) ? 64 : 63;
    int nval = nrow * 128;
    for (int i = t * 8; i < nval; i += 128 * 8)
      *(uint4*)(zc + i) = *(const uint4*)(slab + ch * 8192 + i);
    __syncthreads();
    for (int j0 = 0; j0 < nrow; j0 += 8) {
      float xs[8];
#pragma unroll
      for (int jj = 0; jj < 8; jj++)
        if (j0 + jj < nrow) xs[jj] = bf2f(zc[(j0 + jj) * 128 + t]);
#pragma unroll
      for (int jj = 0; jj < 8; jj++)
        if (j0 + jj < nrow) {
          float xv = xs[jj];
          s0 = q0 * s0 + xv;
          s1 = q1 * s1 + xv;
          float v = w0 * s0 + w1 * s1 + om * xv;
          xs[jj] = v / (1.f + __expf(-v));  // silu
        }
#pragma unroll
      for (int jj = 0; jj < 8; jj++)
        if (j0 + jj < nrow)
          zc[(j0 + jj) * 128 + t] = (u16)((__float_as_uint(xs[jj]) + 0x8000u) >> 16);
    }
    __syncthreads();
    for (int i = t * 8; i < nval; i += 128 * 8)
      *(uint4*)(slab + ch * 8192 + i) = *(const uint4*)(zc + i);
    __syncthreads();
  }
}

// ---------------- K3: head GEMM partials (K split into 30 chunks of 1088) ----------------
__global__ __launch_bounds__(256) void k_head(
    const u16* __restrict__ u, const u16* __restrict__ whs, float* __restrict__ part) {
  const int t = threadIdx.x;
  const int lane = t & 63, wid = t >> 6;
  const int quad = lane >> 4, lc = lane & 15;
  const int tile = blockIdx.x;  // 0..20
  const int ch = blockIdx.y;    // 0..29
  const int m0 = tile * 64 + wid * 16;
  const u16* Ab = u + (size_t)(m0 + lc) * KH + (size_t)ch * KPC;
  const int g0 = ch * (KPC / 8);  // base k-group
  f4v acc[6];
#pragma unroll
  for (int n = 0; n < 6; n++) acc[n] = (f4v){0.f, 0.f, 0.f, 0.f};
  bf8v a_nxt = *(const bf8v*)(Ab + quad * 8);
  bf8v b_nxt[6];
#pragma unroll
  for (int n = 0; n < 6; n++)
    b_nxt[n] = *(const bf8v*)(whs + ((size_t)(g0 + quad) * PRED + n * 16 + lc) * 8);
  for (int ks = 0; ks < HITER; ks++) {
    bf8v a_cur = a_nxt;
    bf8v b_cur[6];
#pragma unroll
    for (int n = 0; n < 6; n++) b_cur[n] = b_nxt[n];
    if (ks < HITER - 1) {
      a_nxt = *(const bf8v*)(Ab + (ks + 1) * 32 + quad * 8);
#pragma unroll
      for (int n = 0; n < 6; n++)
        b_nxt[n] = *(const bf8v*)(whs + ((size_t)(g0 + (ks + 1) * 4 + quad) * PRED + n * 16 + lc) * 8);
    }
#pragma unroll
    for (int n = 0; n < 6; n++) acc[n] = mfma16(a_cur, b_cur[n], acc[n]);
  }
#pragma unroll
  for (int n = 0; n < 6; n++) {
    int col = n * 16 + lc;
#pragma unroll
    for (int r = 0; r < 4; r++)
      part[((size_t)ch * BN + m0 + quad * 4 + r) * PRED + col] = acc[n][r];
  }
}

// ---------------- K4: reduce partials + bias -> fp32 out ----------------
__global__ __launch_bounds__(256) void k_red(
    const float* __restrict__ part, const float* __restrict__ hb, float* __restrict__ out) {
  int i = blockIdx.x * 256 + threadIdx.x;
  if (i >= BN * PRED) return;
  int row = i / PRED, col = i - row * PRED;
  float s = hb[col];
#pragma unroll 5
  for (int c = 0; c < CH; c++) s += part[((size_t)c * BN + row) * PRED + col];
  out[i] = s;
}

// ---------------- host ----------------
extern "C" void kernel_launch(void* const* d_in, const int* in_sizes, int n_in,
                              void* d_out, int out_size, void* d_ws, size_t ws_size,
                              hipStream_t stream) {
  const float* x      = (const float*)d_in[0];
  const float* fp_w1  = (const float*)d_in[1];
  const float* fp_b1  = (const float*)d_in[2];
  const float* fp_w2  = (const float*)d_in[3];
  const float* fp_b2  = (const float*)d_in[4];
  const float* fp_wr  = (const float*)d_in[5];
  const float* fp_br  = (const float*)d_in[6];
  const float* fp_g   = (const float*)d_in[7];
  const float* fp_be  = (const float*)d_in[8];
  const float* enc_w1 = (const float*)d_in[9];
  const float* enc_b1 = (const float*)d_in[10];
  const float* enc_w2 = (const float*)d_in[11];
  const float* enc_b2 = (const float*)d_in[12];
  const float* enc_wr = (const float*)d_in[13];
  const float* enc_br = (const float*)d_in[14];
  const float* enc_g  = (const float*)d_in[15];
  const float* enc_be = (const float*)d_in[16];
  const float* e_del  = (const float*)d_in[17];
  const float* e_alp  = (const float*)d_in[18];
  const float* e_bet  = (const float*)d_in[19];
  const float* e_gam  = (const float*)d_in[20];
  const float* e_om   = (const float*)d_in[21];
  const float* head_w = (const float*)d_in[22];
  const float* head_b = (const float*)d_in[23];

  // ws layout (bytes):
  //   [0, 87736320)             z3 / u  (bf16, [ROWS][128])
  //   [87736320, 103219200)     part    (fp32, [30][1344][96])
  //   [103219200, ...)          swizzled bf16 weights (~6.6 MB)
  char* base = (char*)d_ws;
  u16* z3 = (u16*)base;
  const size_t EZB = (size_t)ROWS * 128 * 2;        // 87,736,320
  float* part = (float*)(base + EZB);
  const size_t PARTB = (size_t)CH * BN * PRED * 4;  // 15,482,880
  u16* wb = (u16*)(base + EZB + PARTB);
  // wb offsets (u16): ws1=0(8192), ws2=8192(32768), wsr=40960(4096),
  //                   wse=45056(6*16384), wsh=143360(32640*96)
  u16* ws1 = wb;
  u16* ws2 = wb + 8192;
  u16* wsr = wb + 40960;
  u16* wse = wb + 45056;
  u16* wsh = wb + 143360;

  swz_all<<<560 + (KH * PRED + 255) / 256, 256, 0, stream>>>(
      fp_w1, fp_w2, fp_wr, enc_w1, enc_w2, enc_wr, head_w, wb, wsh);

  k_lem<<<ROWS / 64, 128, 0, stream>>>(x, ws1, fp_b1, ws2, wsr, fp_b2, fp_br, fp_g, fp_be,
                                       wse, enc_b1, enc_b2, enc_br, enc_g, enc_be, z3);
  k_ema<<<BN, 128, 0, stream>>>(z3, e_del, e_alp, e_bet, e_gam, e_om);
  k_head<<<dim3(21, CH), 256, 0, stream>>>(z3, wsh, part);
  k_red<<<(BN * PRED + 255) / 256, 256, 0, stream>>>(part, head_b, (float*)d_out);
}

// Round 6
// 390.255 us; speedup vs baseline: 1.2537x; 1.1385x over previous
//
#include <hip/hip_runtime.h>

typedef unsigned short u16;
typedef short bf8v __attribute__((ext_vector_type(8)));
typedef float f4v __attribute__((ext_vector_type(4)));
typedef float f16v __attribute__((ext_vector_type(16)));

#define DEV static __device__ __forceinline__

constexpr int BB   = 64;
constexpr int NV   = 21;
constexpr int BN   = BB * NV;       // 1344
constexpr int PNUM = 255;
constexpr int D    = 128;
constexpr int PRED = 96;
constexpr int ROWS = BN * PNUM;     // 342720 = 64 * 5355
constexpr int KH   = D * PNUM;      // 32640 head K
constexpr int CH   = 30;            // head K chunks
constexpr int KPC  = KH / CH;       // 1088 = 34*32
constexpr int HITER = KPC / 32;     // 34
constexpr float EMA_SCALE = 0.70710678118654752440f;  // 1/sqrt(2)

DEV float bf2f(u16 h) { return __uint_as_float(((unsigned)h) << 16); }
DEV u16 f2bf(float f) {  // RNE (weight prepass only)
  unsigned u = __float_as_uint(f);
  return (u16)((u + 0x7fffu + ((u >> 16) & 1u)) >> 16);
}
// pack two floats to bf16 pair (round-half-up): lo = a, hi = b
DEV unsigned pkbf2(float a, float b) {
  unsigned ua = __float_as_uint(a) + 0x8000u;
  unsigned ub = __float_as_uint(b) + 0x8000u;
  return __builtin_amdgcn_perm(ub, ua, 0x07060302u);
}
DEV bf8v mk4(unsigned a, unsigned b, unsigned c, unsigned d) {
  int4 t = {(int)a, (int)b, (int)c, (int)d};
  bf8v r;
  __builtin_memcpy(&r, &t, 16);
  return r;
}
DEV bf8v ld8(const u16* p) {
  bf8v r;
  __builtin_memcpy(&r, p, 16);
  return r;
}
DEV f4v mfma16(bf8v a, bf8v b, f4v c) {
  return __builtin_amdgcn_mfma_f32_16x16x32_bf16(a, b, c, 0, 0, 0);
}
DEV f16v mfma32(bf8v a, bf8v b, f16v c) {
  return __builtin_amdgcn_mfma_f32_32x32x16_bf16(a, b, c, 0, 0, 0);
}
DEV f16v zero16() {
  f16v r;
#pragma unroll
  for (int i = 0; i < 16; i++) r[i] = 0.f;
  return r;
}

// Assemble B-operand fragment (8 contiguous channels [16*ks+8*hh .. +7] of this
// lane's row) from packed D-layout register array pk[g][w][2] via one
// shfl_xor(32) pair exchange. Loops calling this are fully unrolled, so the
// indices are compile-time constants post-unroll (SROA keeps pk in registers).
#define FRAG_ASM(pk, ks, hh)                                                   \
  ({                                                                           \
    int _g = (ks) >> 1, _lw = 2 * ((ks) & 1);                                  \
    unsigned _A0 = pk[_g][_lw][0], _A1 = pk[_g][_lw][1];                       \
    unsigned _B0 = pk[_g][_lw + 1][0], _B1 = pk[_g][_lw + 1][1];               \
    unsigned _own0 = (hh) ? _B0 : _A0, _own1 = (hh) ? _B1 : _A1;               \
    unsigned _snd0 = (hh) ? _A0 : _B0, _snd1 = (hh) ? _A1 : _B1;               \
    unsigned _o0 = (unsigned)__shfl_xor((int)_snd0, 32, 64);                   \
    unsigned _o1 = (unsigned)__shfl_xor((int)_snd1, 32, 64);                   \
    mk4((hh) ? _o0 : _own0, (hh) ? _o1 : _own1,                                \
        (hh) ? _own0 : _o0, (hh) ? _own1 : _o1);                               \
  })

// ---------------- fused weight swizzle prepass (fp32 -> bf16 fragments) ----------------
// frag[((k>>3)*N + n)*8 + (k&7)] = src[k*N + n]; k >= K zero-filled.
__global__ void swz_all(
    const float* __restrict__ fw1, const float* __restrict__ fw2,
    const float* __restrict__ fwr, const float* __restrict__ ew1,
    const float* __restrict__ ew2, const float* __restrict__ ewr,
    const float* __restrict__ hw, u16* __restrict__ wb, u16* __restrict__ wsh) {
  int b = blockIdx.x;
  if (b >= 560) {  // head_w [d*255+l][96] -> fragments in k-order kp = l*128 + d
    int i = (b - 560) * 256 + threadIdx.x;
    if (i >= KH * PRED) return;
    int kp = i / PRED, n = i - kp * PRED;
    int l = kp >> 7, d = kp & 127;
    wsh[((size_t)(kp >> 3) * PRED + n) * 8 + (kp & 7)] =
        f2bf(hw[(size_t)(d * PNUM + l) * PRED + n]);
    return;
  }
  const float* src; u16* dst; int K, N, Kp;
  if (b < 32)       { src = fw1; dst = wb;          K = 16;  N = 256; Kp = 32; }
  else if (b < 160) { b -= 32;  src = fw2; dst = wb + 8192;  K = 256; N = 128; Kp = 256; }
  else if (b < 176) { b -= 160; src = fwr; dst = wb + 40960; K = 16;  N = 128; Kp = 32; }
  else {
    int e = (b - 176) >> 6; b = (b - 176) & 63;
    int l = e / 3, w = e - 3 * l;
    const float* basep = (w == 0) ? ew1 : (w == 1) ? ew2 : ewr;
    src = basep + (size_t)l * 16384;
    dst = wb + 45056 + e * 16384;
    K = 128; N = 128; Kp = 128;
  }
  int i = b * 256 + threadIdx.x;
  if (i >= Kp * N) return;
  int k = i / N, n = i - k * N;
  u16 v = (k < K) ? f2bf(src[(size_t)k * N + n]) : (u16)0;
  dst[((size_t)(k >> 3) * N + n) * 8 + (k & 7)] = v;
}

// ---------------- K1: fused gather + fp LEMblock + 2 encoder LEMblocks ----------------
// 32x32x16 MFMA, transposed (A=weight, B=act). Each wave owns 32 rows; lane's
// act-row = lane&31. Between-GEMM relayout done IN REGISTERS via shfl_xor(32)
// (no act LDS, no barriers). LDS only stages the final 64x128 output tile.
__global__ __launch_bounds__(128, 2) void k_lem(
    const float* __restrict__ x,
    const u16* __restrict__ ws1, const float* __restrict__ b1,
    const u16* __restrict__ ws2, const u16* __restrict__ wsr,
    const float* __restrict__ b2, const float* __restrict__ br,
    const float* __restrict__ g, const float* __restrict__ be,
    const u16* __restrict__ wse, const float* __restrict__ eb1,
    const float* __restrict__ eb2, const float* __restrict__ ebr,
    const float* __restrict__ eg, const float* __restrict__ ebe,
    u16* __restrict__ zout) {
  __shared__ __align__(16) u16 zst[64 * 132];
  const int t = threadIdx.x;
  const int lane = t & 63, w = t >> 6;  // w: wave 0..1
  const int hh = lane >> 5, r5 = lane & 31;
  const int tile = blockIdx.x;
  const int row = tile * 64 + w * 32 + r5;

  // gather z0: lane holds patch elems [8*hh .. 8*hh+7] of its row (B-frag K=16)
  bf8v azv;
  {
    unsigned R = (unsigned)row;
    unsigned bn = R / 255u;
    unsigned p = R - bn * 255u;
    const float* px = x + (size_t)bn * 2048u + p * 8u + hh * 8;
    float4 v0 = *(const float4*)px;
    float4 v1 = *(const float4*)(px + 4);
    azv = mk4(pkbf2(v0.x, v0.y), pkbf2(v0.z, v0.w),
              pkbf2(v1.x, v1.y), pkbf2(v1.z, v1.w));
  }

  unsigned hpk[8][4][2];  // packed h (256 chans, D-layout halves)
  unsigned zpk[4][4][2];  // packed z (128 chans)

  // ---- GEMM1: h = relu(W1^T z0 + b1), two halves of 128 cols ----
#pragma unroll
  for (int half = 0; half < 2; half++) {
    f16v a[4];
#pragma unroll
    for (int gg = 0; gg < 4; gg++) {
      bf8v wf = ld8(ws1 + ((size_t)(hh * 256 + (half * 4 + gg) * 32 + r5)) * 8);
      a[gg] = mfma32(wf, azv, zero16());
    }
#pragma unroll
    for (int gg = 0; gg < 4; gg++)
#pragma unroll
      for (int wq = 0; wq < 4; wq++) {
        int c0 = (half * 4 + gg) * 32 + wq * 8 + 4 * hh;
        float4 bv = *(const float4*)(b1 + c0);
        float v0 = fmaxf(a[gg][wq * 4 + 0] + bv.x, 0.f);
        float v1 = fmaxf(a[gg][wq * 4 + 1] + bv.y, 0.f);
        float v2 = fmaxf(a[gg][wq * 4 + 2] + bv.z, 0.f);
        float v3 = fmaxf(a[gg][wq * 4 + 3] + bv.w, 0.f);
        hpk[half * 4 + gg][wq][0] = pkbf2(v0, v1);
        hpk[half * 4 + gg][wq][1] = pkbf2(v2, v3);
      }
  }

  // ---- GEMM2: y1 = W2^T h + Wr^T z0 + b2 + br -> LN -> z1 ----
  {
    f16v acc[4];
#pragma unroll
    for (int gg = 0; gg < 4; gg++) {
      bf8v wf = ld8(wsr + ((size_t)(hh * 128 + gg * 32 + r5)) * 8);
      acc[gg] = mfma32(wf, azv, zero16());
    }
    bf8v wq[2][4];
#pragma unroll
    for (int gg = 0; gg < 4; gg++)
      wq[0][gg] = ld8(ws2 + ((size_t)(hh * 128 + gg * 32 + r5)) * 8);
    bf8v bf_cur = FRAG_ASM(hpk, 0, hh);
#pragma unroll
    for (int ks = 0; ks < 16; ks++) {
      int cur = ks & 1;
      if (ks < 15) {
#pragma unroll
        for (int gg = 0; gg < 4; gg++)
          wq[cur ^ 1][gg] =
              ld8(ws2 + ((size_t)((2 * (ks + 1) + hh) * 128 + gg * 32 + r5)) * 8);
        bf8v bf_nxt = FRAG_ASM(hpk, ks + 1, hh);
#pragma unroll
        for (int gg = 0; gg < 4; gg++) acc[gg] = mfma32(wq[cur][gg], bf_cur, acc[gg]);
        bf_cur = bf_nxt;
      } else {
#pragma unroll
        for (int gg = 0; gg < 4; gg++) acc[gg] = mfma32(wq[cur][gg], bf_cur, acc[gg]);
      }
    }
    // bias + LN
    float s = 0.f, s2 = 0.f;
#pragma unroll
    for (int gg = 0; gg < 4; gg++)
#pragma unroll
      for (int wq4 = 0; wq4 < 4; wq4++) {
        int c0 = gg * 32 + wq4 * 8 + 4 * hh;
        float4 bv2 = *(const float4*)(b2 + c0);
        float4 bvr = *(const float4*)(br + c0);
        acc[gg][wq4 * 4 + 0] += bv2.x + bvr.x;
        acc[gg][wq4 * 4 + 1] += bv2.y + bvr.y;
        acc[gg][wq4 * 4 + 2] += bv2.z + bvr.z;
        acc[gg][wq4 * 4 + 3] += bv2.w + bvr.w;
#pragma unroll
        for (int sidx = 0; sidx < 4; sidx++) {
          float v = acc[gg][wq4 * 4 + sidx];
          s += v; s2 += v * v;
        }
      }
    s += __shfl_xor(s, 32, 64); s2 += __shfl_xor(s2, 32, 64);
    float mean = s * (1.f / 128.f);
    float rstd = rsqrtf(s2 * (1.f / 128.f) - mean * mean + 1e-5f);
#pragma unroll
    for (int gg = 0; gg < 4; gg++)
#pragma unroll
      for (int wq4 = 0; wq4 < 4; wq4++) {
        int c0 = gg * 32 + wq4 * 8 + 4 * hh;
        float4 gv = *(const float4*)(g + c0);
        float4 bv = *(const float4*)(be + c0);
        float v0 = (acc[gg][wq4 * 4 + 0] - mean) * rstd * gv.x + bv.x;
        float v1 = (acc[gg][wq4 * 4 + 1] - mean) * rstd * gv.y + bv.y;
        float v2 = (acc[gg][wq4 * 4 + 2] - mean) * rstd * gv.z + bv.z;
        float v3 = (acc[gg][wq4 * 4 + 3] - mean) * rstd * gv.w + bv.w;
        zpk[gg][wq4][0] = pkbf2(v0, v1);
        zpk[gg][wq4][1] = pkbf2(v2, v3);
      }
  }

  // ---- encoder layers ----
#pragma unroll 1
  for (int L = 0; L < 2; L++) {
    const u16* w1p = wse + (size_t)(L * 3 + 0) * 16384;
    const u16* w2p = wse + (size_t)(L * 3 + 1) * 16384;
    const u16* wrp = wse + (size_t)(L * 3 + 2) * 16384;
    unsigned hp2[4][4][2];
    // GEMM-A: h2 = relu(W1^T z + eb1)
    {
      f16v a2[4];
#pragma unroll
      for (int gg = 0; gg < 4; gg++) a2[gg] = zero16();
      bf8v wq[2][4];
#pragma unroll
      for (int gg = 0; gg < 4; gg++)
        wq[0][gg] = ld8(w1p + ((size_t)(hh * 128 + gg * 32 + r5)) * 8);
      bf8v bf_cur = FRAG_ASM(zpk, 0, hh);
#pragma unroll
      for (int ks = 0; ks < 8; ks++) {
        int cur = ks & 1;
        if (ks < 7) {
#pragma unroll
          for (int gg = 0; gg < 4; gg++)
            wq[cur ^ 1][gg] =
                ld8(w1p + ((size_t)((2 * (ks + 1) + hh) * 128 + gg * 32 + r5)) * 8);
          bf8v bf_nxt = FRAG_ASM(zpk, ks + 1, hh);
#pragma unroll
          for (int gg = 0; gg < 4; gg++) a2[gg] = mfma32(wq[cur][gg], bf_cur, a2[gg]);
          bf_cur = bf_nxt;
        } else {
#pragma unroll
          for (int gg = 0; gg < 4; gg++) a2[gg] = mfma32(wq[cur][gg], bf_cur, a2[gg]);
        }
      }
#pragma unroll
      for (int gg = 0; gg < 4; gg++)
#pragma unroll
        for (int wq4 = 0; wq4 < 4; wq4++) {
          int c0 = gg * 32 + wq4 * 8 + 4 * hh;
          float4 bv = *(const float4*)(eb1 + L * 128 + c0);
          float v0 = fmaxf(a2[gg][wq4 * 4 + 0] + bv.x, 0.f);
          float v1 = fmaxf(a2[gg][wq4 * 4 + 1] + bv.y, 0.f);
          float v2 = fmaxf(a2[gg][wq4 * 4 + 2] + bv.z, 0.f);
          float v3 = fmaxf(a2[gg][wq4 * 4 + 3] + bv.w, 0.f);
          hp2[gg][wq4][0] = pkbf2(v0, v1);
          hp2[gg][wq4][1] = pkbf2(v2, v3);
        }
    }
    // GEMM-B: y = W2^T h2 + Wr^T z + biases -> LN
    f16v acc[4];
#pragma unroll
    for (int gg = 0; gg < 4; gg++) acc[gg] = zero16();
    {
      bf8v wq[2][4];
#pragma unroll
      for (int gg = 0; gg < 4; gg++)
        wq[0][gg] = ld8(w2p + ((size_t)(hh * 128 + gg * 32 + r5)) * 8);
      bf8v bf_cur = FRAG_ASM(hp2, 0, hh);
#pragma unroll
      for (int ks = 0; ks < 8; ks++) {
        int cur = ks & 1;
        if (ks < 7) {
#pragma unroll
          for (int gg = 0; gg < 4; gg++)
            wq[cur ^ 1][gg] =
                ld8(w2p + ((size_t)((2 * (ks + 1) + hh) * 128 + gg * 32 + r5)) * 8);
          bf8v bf_nxt = FRAG_ASM(hp2, ks + 1, hh);
#pragma unroll
          for (int gg = 0; gg < 4; gg++) acc[gg] = mfma32(wq[cur][gg], bf_cur, acc[gg]);
          bf_cur = bf_nxt;
        } else {
#pragma unroll
          for (int gg = 0; gg < 4; gg++) acc[gg] = mfma32(wq[cur][gg], bf_cur, acc[gg]);
        }
      }
#pragma unroll
      for (int gg = 0; gg < 4; gg++)
        wq[0][gg] = ld8(wrp + ((size_t)(hh * 128 + gg * 32 + r5)) * 8);
      bf_cur = FRAG_ASM(zpk, 0, hh);
#pragma unroll
      for (int ks = 0; ks < 8; ks++) {
        int cur = ks & 1;
        if (ks < 7) {
#pragma unroll
          for (int gg = 0; gg < 4; gg++)
            wq[cur ^ 1][gg] =
                ld8(wrp + ((size_t)((2 * (ks + 1) + hh) * 128 + gg * 32 + r5)) * 8);
          bf8v bf_nxt = FRAG_ASM(zpk, ks + 1, hh);
#pragma unroll
          for (int gg = 0; gg < 4; gg++) acc[gg] = mfma32(wq[cur][gg], bf_cur, acc[gg]);
          bf_cur = bf_nxt;
        } else {
#pragma unroll
          for (int gg = 0; gg < 4; gg++) acc[gg] = mfma32(wq[cur][gg], bf_cur, acc[gg]);
        }
      }
    }
    float s = 0.f, s2 = 0.f;
#pragma unroll
    for (int gg = 0; gg < 4; gg++)
#pragma unroll
      for (int wq4 = 0; wq4 < 4; wq4++) {
        int c0 = gg * 32 + wq4 * 8 + 4 * hh;
        float4 bv2 = *(const float4*)(eb2 + L * 128 + c0);
        float4 bvr = *(const float4*)(ebr + L * 128 + c0);
        acc[gg][wq4 * 4 + 0] += bv2.x + bvr.x;
        acc[gg][wq4 * 4 + 1] += bv2.y + bvr.y;
        acc[gg][wq4 * 4 + 2] += bv2.z + bvr.z;
        acc[gg][wq4 * 4 + 3] += bv2.w + bvr.w;
#pragma unroll
        for (int sidx = 0; sidx < 4; sidx++) {
          float v = acc[gg][wq4 * 4 + sidx];
          s += v; s2 += v * v;
        }
      }
    s += __shfl_xor(s, 32, 64); s2 += __shfl_xor(s2, 32, 64);
    float mean = s * (1.f / 128.f);
    float rstd = rsqrtf(s2 * (1.f / 128.f) - mean * mean + 1e-5f);
#pragma unroll
    for (int gg = 0; gg < 4; gg++)
#pragma unroll
      for (int wq4 = 0; wq4 < 4; wq4++) {
        int c0 = gg * 32 + wq4 * 8 + 4 * hh;
        float4 gv = *(const float4*)(eg + L * 128 + c0);
        float4 bv = *(const float4*)(ebe + L * 128 + c0);
        float v0 = (acc[gg][wq4 * 4 + 0] - mean) * rstd * gv.x + bv.x;
        float v1 = (acc[gg][wq4 * 4 + 1] - mean) * rstd * gv.y + bv.y;
        float v2 = (acc[gg][wq4 * 4 + 2] - mean) * rstd * gv.z + bv.z;
        float v3 = (acc[gg][wq4 * 4 + 3] - mean) * rstd * gv.w + bv.w;
        unsigned plo = pkbf2(v0, v1), phi = pkbf2(v2, v3);
        if (L == 0) {
          zpk[gg][wq4][0] = plo;
          zpk[gg][wq4][1] = phi;
        } else {
          uint2 pv = {plo, phi};
          *(uint2*)(zst + (w * 32 + r5) * 132 + c0) = pv;
        }
      }
  }

  // per-wave coalesced store of its own 32 rows (same-wave LDS RAW: no barrier)
#pragma unroll
  for (int it = 0; it < 8; it++) {
    int lu = it * 64 + lane;
    int rr = lu >> 4, seg = lu & 15;
    int orow = w * 32 + rr;
    *(uint4*)(zout + ((size_t)tile * 64 + orow) * 128 + seg * 8) =
        *(const uint4*)(zst + orow * 132 + seg * 8);
  }
}

// ---------------- K2: MultiHeadEMA (2-state scan) + residual + silu, IN-PLACE ----------------
__global__ __launch_bounds__(128) void k_ema(
    u16* __restrict__ z,
    const float* __restrict__ pdel, const float* __restrict__ palp,
    const float* __restrict__ pbet, const float* __restrict__ pgam,
    const float* __restrict__ pome) {
  __shared__ __align__(16) u16 zc[64 * 128];
  const int t = threadIdx.x;  // channel d
  const int bn = blockIdx.x;
  float p0 = 1.f / (1.f + __expf(-pdel[t * 2 + 0]));
  float p1 = 1.f / (1.f + __expf(-pdel[t * 2 + 1]));
  float q0 = 1.f - p0 / (1.f + __expf(-palp[t * 2 + 0]));
  float q1 = 1.f - p1 / (1.f + __expf(-palp[t * 2 + 1]));
  float w0 = p0 * pbet[t * 2 + 0] * pgam[t * 2 + 0] * EMA_SCALE;
  float w1 = p1 * pbet[t * 2 + 1] * pgam[t * 2 + 1] * EMA_SCALE;
  float om = pome[t];
  float s0 = 0.f, s1 = 0.f;
  u16* slab = z + (size_t)bn * KH;

  for (int ch = 0; ch < 4; ch++) {
    int nrow = (ch < 3) ? 64 : 63;
    int nval = nrow * 128;
    for (int i = t * 8; i < nval; i += 128 * 8)
      *(uint4*)(zc + i) = *(const uint4*)(slab + ch * 8192 + i);
    __syncthreads();
    for (int j0 = 0; j0 < nrow; j0 += 8) {
      float xs[8];
#pragma unroll
      for (int jj = 0; jj < 8; jj++)
        if (j0 + jj < nrow) xs[jj] = bf2f(zc[(j0 + jj) * 128 + t]);
#pragma unroll
      for (int jj = 0; jj < 8; jj++)
        if (j0 + jj < nrow) {
          float xv = xs[jj];
          s0 = q0 * s0 + xv;
          s1 = q1 * s1 + xv;
          float v = w0 * s0 + w1 * s1 + om * xv;
          xs[jj] = v / (1.f + __expf(-v));  // silu
        }
#pragma unroll
      for (int jj = 0; jj < 8; jj++)
        if (j0 + jj < nrow)
          zc[(j0 + jj) * 128 + t] = (u16)((__float_as_uint(xs[jj]) + 0x8000u) >> 16);
    }
    __syncthreads();
    for (int i = t * 8; i < nval; i += 128 * 8)
      *(uint4*)(slab + ch * 8192 + i) = *(const uint4*)(zc + i);
    __syncthreads();
  }
}

// ---------------- K3: head GEMM partials (K split into 30 chunks of 1088) ----------------
__global__ __launch_bounds__(256) void k_head(
    const u16* __restrict__ u, const u16* __restrict__ whs, float* __restrict__ part) {
  const int t = threadIdx.x;
  const int lane = t & 63, wid = t >> 6;
  const int quad = lane >> 4, lc = lane & 15;
  const int tile = blockIdx.x;  // 0..20
  const int ch = blockIdx.y;    // 0..29
  const int m0 = tile * 64 + wid * 16;
  const u16* Ab = u + (size_t)(m0 + lc) * KH + (size_t)ch * KPC;
  const int g0 = ch * (KPC / 8);  // base k-group
  f4v acc[6];
#pragma unroll
  for (int n = 0; n < 6; n++) acc[n] = (f4v){0.f, 0.f, 0.f, 0.f};
  bf8v a_nxt = ld8(Ab + quad * 8);
  bf8v b_nxt[6];
#pragma unroll
  for (int n = 0; n < 6; n++)
    b_nxt[n] = ld8(whs + ((size_t)(g0 + quad) * PRED + n * 16 + lc) * 8);
  for (int ks = 0; ks < HITER; ks++) {
    bf8v a_cur = a_nxt;
    bf8v b_cur[6];
#pragma unroll
    for (int n = 0; n < 6; n++) b_cur[n] = b_nxt[n];
    if (ks < HITER - 1) {
      a_nxt = ld8(Ab + (ks + 1) * 32 + quad * 8);
#pragma unroll
      for (int n = 0; n < 6; n++)
        b_nxt[n] = ld8(whs + ((size_t)(g0 + (ks + 1) * 4 + quad) * PRED + n * 16 + lc) * 8);
    }
#pragma unroll
    for (int n = 0; n < 6; n++) acc[n] = mfma16(a_cur, b_cur[n], acc[n]);
  }
#pragma unroll
  for (int n = 0; n < 6; n++) {
    int col = n * 16 + lc;
#pragma unroll
    for (int r = 0; r < 4; r++)
      part[((size_t)ch * BN + m0 + quad * 4 + r) * PRED + col] = acc[n][r];
  }
}

// ---------------- K4: reduce partials + bias -> fp32 out ----------------
__global__ __launch_bounds__(256) void k_red(
    const float* __restrict__ part, const float* __restrict__ hb, float* __restrict__ out) {
  int i = blockIdx.x * 256 + threadIdx.x;
  if (i >= BN * PRED) return;
  int row = i / PRED, col = i - row * PRED;
  float s = hb[col];
#pragma unroll 5
  for (int c = 0; c < CH; c++) s += part[((size_t)c * BN + row) * PRED + col];
  out[i] = s;
}

// ---------------- host ----------------
extern "C" void kernel_launch(void* const* d_in, const int* in_sizes, int n_in,
                              void* d_out, int out_size, void* d_ws, size_t ws_size,
                              hipStream_t stream) {
  const float* x      = (const float*)d_in[0];
  const float* fp_w1  = (const float*)d_in[1];
  const float* fp_b1  = (const float*)d_in[2];
  const float* fp_w2  = (const float*)d_in[3];
  const float* fp_b2  = (const float*)d_in[4];
  const float* fp_wr  = (const float*)d_in[5];
  const float* fp_br  = (const float*)d_in[6];
  const float* fp_g   = (const float*)d_in[7];
  const float* fp_be  = (const float*)d_in[8];
  const float* enc_w1 = (const float*)d_in[9];
  const float* enc_b1 = (const float*)d_in[10];
  const float* enc_w2 = (const float*)d_in[11];
  const float* enc_b2 = (const float*)d_in[12];
  const float* enc_wr = (const float*)d_in[13];
  const float* enc_br = (const float*)d_in[14];
  const float* enc_g  = (const float*)d_in[15];
  const float* enc_be = (const float*)d_in[16];
  const float* e_del  = (const float*)d_in[17];
  const float* e_alp  = (const float*)d_in[18];
  const float* e_bet  = (const float*)d_in[19];
  const float* e_gam  = (const float*)d_in[20];
  const float* e_om   = (const float*)d_in[21];
  const float* head_w = (const float*)d_in[22];
  const float* head_b = (const float*)d_in[23];

  // ws layout (bytes):
  //   [0, 87736320)             z3 / u  (bf16, [ROWS][128])
  //   [87736320, 103219200)     part    (fp32, [30][1344][96])
  //   [103219200, ...)          swizzled bf16 weights (~6.6 MB)
  char* base = (char*)d_ws;
  u16* z3 = (u16*)base;
  const size_t EZB = (size_t)ROWS * 128 * 2;        // 87,736,320
  float* part = (float*)(base + EZB);
  const size_t PARTB = (size_t)CH * BN * PRED * 4;  // 15,482,880
  u16* wb = (u16*)(base + EZB + PARTB);
  // wb offsets (u16): ws1=0(8192), ws2=8192(32768), wsr=40960(4096),
  //                   wse=45056(6*16384), wsh=143360(32640*96)
  u16* ws1 = wb;
  u16* ws2 = wb + 8192;
  u16* wsr = wb + 40960;
  u16* wse = wb + 45056;
  u16* wsh = wb + 143360;

  swz_all<<<560 + (KH * PRED + 255) / 256, 256, 0, stream>>>(
      fp_w1, fp_w2, fp_wr, enc_w1, enc_w2, enc_wr, head_w, wb, wsh);

  k_lem<<<ROWS / 64, 128, 0, stream>>>(x, ws1, fp_b1, ws2, wsr, fp_b2, fp_br, fp_g, fp_be,
                                       wse, enc_b1, enc_b2, enc_br, enc_g, enc_be, z3);
  k_ema<<<BN, 128, 0, stream>>>(z3, e_del, e_alp, e_bet, e_gam, e_om);
  k_head<<<dim3(21, CH), 256, 0, stream>>>(z3, wsh, part);
  k_red<<<(BN * PRED + 255) / 256, 256, 0, stream>>>(part, head_b, (float*)d_out);
}